// Round 2
// baseline (1366.322 us; speedup 1.0000x reference)
//
#include <hip/hip_runtime.h>
#include <math.h>

#define N_NODES 50000
#define N_EDGES 800000
#define DCH 128
#define N_LAYERS 9
#define N_GRAPHS 256
#define EPSF 1e-5f

// ---------------- CSR build ----------------
__global__ void hist_kernel(const int* __restrict__ dst, int* __restrict__ deg) {
    int t = blockIdx.x * 256 + threadIdx.x;   // grid covers exactly N_EDGES
    atomicAdd(&deg[dst[t]], 1);
}

__global__ __launch_bounds__(1024) void scan_kernel(const int* __restrict__ deg,
                                                    int* __restrict__ rowp,
                                                    int* __restrict__ cursor) {
    const int CH = 49;  // 1024*49 = 50176 >= 50000
    int t = threadIdx.x;
    int b = t * CH, e = min(b + CH, N_NODES);
    int s = 0;
    for (int i = b; i < e; i++) s += deg[i];
    __shared__ int sh[1024];
    sh[t] = s;
    __syncthreads();
    for (int off = 1; off < 1024; off <<= 1) {
        int v = (t >= off) ? sh[t - off] : 0;
        __syncthreads();
        sh[t] += v;
        __syncthreads();
    }
    int run = t ? sh[t - 1] : 0;
    for (int i = b; i < e; i++) {
        rowp[i] = run;
        cursor[i] = run;
        run += deg[i];
    }
    if (t == 0) rowp[N_NODES] = N_EDGES;
}

__global__ void scatter_kernel(const int* __restrict__ src, const int* __restrict__ dst,
                               const float* __restrict__ eattr,
                               int* __restrict__ cursor, int* __restrict__ srcp,
                               float* __restrict__ eattrp) {
    int t = blockIdx.x * 256 + threadIdx.x;   // grid covers exactly N_EDGES
    int d = dst[t];
    int p = atomicAdd(&cursor[d], 1);
    srcp[p] = src[t];
    ((float4*)eattrp)[p] = ((const float4*)eattr)[t];
}

// ---------------- h0 = x @ Wv ----------------
__global__ void h0_kernel(const float* __restrict__ x, const float* __restrict__ Wv,
                          float* __restrict__ h) {
    int t = blockIdx.x * 256 + threadIdx.x;
    int n = t >> 6, l = t & 63;
    const float* xr = x + n * 13;
    float s0 = 0.f, s1 = 0.f;
#pragma unroll
    for (int j = 0; j < 13; j++) {
        float xv = xr[j];
        s0 = fmaf(xv, Wv[j * 128 + 2 * l], s0);
        s1 = fmaf(xv, Wv[j * 128 + 2 * l + 1], s1);
    }
    ((float2*)h)[n * 64 + l] = make_float2(s0, s1);
}

// ---------------- per-layer aggregation ----------------
// v = (1+eps)*h + sum_{edges into n} relu(h[src] + edge_attr[e] @ We)
__global__ __launch_bounds__(256) void aggr_kernel(const float* __restrict__ h,
                                                   const float* __restrict__ eattrp,
                                                   const int* __restrict__ rowp,
                                                   const int* __restrict__ srcp,
                                                   const float* __restrict__ We,
                                                   float* __restrict__ v) {
    int n = blockIdx.x * 4 + (threadIdx.x >> 6);  // one wave per node
    int l = threadIdx.x & 63;                     // lane -> channels 2l, 2l+1
    // preload We columns 2l and 2l+1 (8 regs)
    float w00 = We[0 * 128 + 2 * l], w01 = We[0 * 128 + 2 * l + 1];
    float w10 = We[1 * 128 + 2 * l], w11 = We[1 * 128 + 2 * l + 1];
    float w20 = We[2 * 128 + 2 * l], w21 = We[2 * 128 + 2 * l + 1];
    float w30 = We[3 * 128 + 2 * l], w31 = We[3 * 128 + 2 * l + 1];
    int start = rowp[n], end = rowp[n + 1];
    float a0 = 0.f, a1 = 0.f;
    const float2* h2 = (const float2*)h;
    const float4* e4 = (const float4*)eattrp;
    for (int base = start; base < end; base += 64) {
        int cnt = min(64, end - base);
        int sv = 0;
        float4 av = make_float4(0.f, 0.f, 0.f, 0.f);
        if (base + l < end) {
            sv = srcp[base + l];
            av = e4[base + l];
        }
        for (int e2 = 0; e2 < cnt; e2++) {
            int s = __shfl(sv, e2);
            float ax = __shfl(av.x, e2);
            float ay = __shfl(av.y, e2);
            float az = __shfl(av.z, e2);
            float aw = __shfl(av.w, e2);
            float2 hv = h2[(size_t)s * 64 + l];
            float ea0 = fmaf(ax, w00, fmaf(ay, w10, fmaf(az, w20, aw * w30)));
            float ea1 = fmaf(ax, w01, fmaf(ay, w11, fmaf(az, w21, aw * w31)));
            a0 += fmaxf(hv.x + ea0, 0.f);
            a1 += fmaxf(hv.y + ea1, 0.f);
        }
    }
    float2 hn = h2[(size_t)n * 64 + l];
    ((float2*)v)[(size_t)n * 64 + l] =
        make_float2(fmaf(hn.x, 1.f + EPSF, a0), fmaf(hn.y, 1.f + EPSF, a1));
}

// ---------------- per-layer GEMM: v <- relu(v @ W + b) + hin  (in-place on v) ----------------
__global__ __launch_bounds__(256) void gemm_kernel(float* __restrict__ v,
                                                   const float* __restrict__ W,
                                                   const float* __restrict__ b,
                                                   const float* __restrict__ hin) {
    __shared__ float4 vl4[32 * 32];  // 32 nodes x 128 ch = 16 KiB
    int tid = threadIdx.x;
    int row0 = blockIdx.x * 32;
    const float4* vg4 = (const float4*)v;
#pragma unroll
    for (int i = 0; i < 4; i++) {
        int idx = tid + i * 256;  // 0..1023
        int r = idx >> 5;
        int node = row0 + r;
        float4 val = make_float4(0.f, 0.f, 0.f, 0.f);
        if (node < N_NODES) val = vg4[(size_t)node * 32 + (idx & 31)];
        vl4[idx] = val;
    }
    __syncthreads();
    int cg = tid & 31;   // 4 channels: 4*cg..4*cg+3
    int mg = tid >> 5;   // 8 groups x 4 nodes
    float4 acc[4];
#pragma unroll
    for (int m = 0; m < 4; m++) acc[m] = make_float4(0.f, 0.f, 0.f, 0.f);
    const float4* Wg4 = (const float4*)W;
#pragma unroll 4
    for (int k = 0; k < 128; k += 4) {
        float4 w0 = Wg4[k * 32 + cg];
        float4 w1 = Wg4[(k + 1) * 32 + cg];
        float4 w2 = Wg4[(k + 2) * 32 + cg];
        float4 w3 = Wg4[(k + 3) * 32 + cg];
#pragma unroll
        for (int m = 0; m < 4; m++) {
            float4 vv = vl4[(mg * 4 + m) * 32 + (k >> 2)];
            acc[m].x += w0.x * vv.x + w1.x * vv.y + w2.x * vv.z + w3.x * vv.w;
            acc[m].y += w0.y * vv.x + w1.y * vv.y + w2.y * vv.z + w3.y * vv.w;
            acc[m].z += w0.z * vv.x + w1.z * vv.y + w2.z * vv.z + w3.z * vv.w;
            acc[m].w += w0.w * vv.x + w1.w * vv.y + w2.w * vv.z + w3.w * vv.w;
        }
    }
    float4 bb = ((const float4*)b)[cg];
    const float4* h4 = (const float4*)hin;
    float4* o4 = (float4*)v;
#pragma unroll
    for (int m = 0; m < 4; m++) {
        int node = row0 + mg * 4 + m;
        if (node < N_NODES) {
            float4 hh = h4[(size_t)node * 32 + cg];
            float4 r;
            r.x = fmaxf(acc[m].x + bb.x, 0.f) + hh.x;
            r.y = fmaxf(acc[m].y + bb.y, 0.f) + hh.y;
            r.z = fmaxf(acc[m].z + bb.z, 0.f) + hh.z;
            r.w = fmaxf(acc[m].w + bb.w, 0.f) + hh.w;
            o4[(size_t)node * 32 + cg] = r;
        }
    }
}

// ---------------- graph boundaries (batch is sorted) ----------------
__global__ void bounds_kernel(const int* __restrict__ batch, int* __restrict__ gs) {
    int n = blockIdx.x * 256 + threadIdx.x;
    if (n >= N_NODES) return;
    int bcur = batch[n];
    int prev = (n == 0) ? -1 : batch[n - 1];
    for (int g = prev + 1; g <= bcur; g++) gs[g] = n;
    if (n == N_NODES - 1) {
        for (int g = bcur + 1; g <= N_GRAPHS; g++) gs[g] = N_NODES;
    }
}

// ---------------- mean pool (block per graph, no atomics) ----------------
__global__ __launch_bounds__(128) void pool_kernel(const float* __restrict__ h,
                                                   const int* __restrict__ gs,
                                                   float* __restrict__ pooled) {
    int g = blockIdx.x;
    int c = threadIdx.x;
    int s = gs[g], e = gs[g + 1];
    float acc = 0.f;
    for (int n = s; n < e; n++) acc += h[(size_t)n * 128 + c];
    pooled[g * 128 + c] = acc / fmaxf((float)(e - s), 1.0f);
}

// ---------------- MLP head ----------------
__global__ __launch_bounds__(512) void mlp_kernel(const float* __restrict__ pooled,
                                                  const float* __restrict__ Wh1,
                                                  const float* __restrict__ bh1,
                                                  const float* __restrict__ Wh2,
                                                  const float* __restrict__ bh2,
                                                  float* __restrict__ out) {
    int g = blockIdx.x;
    __shared__ float pl[128];
    __shared__ float red[8];
    int tid = threadIdx.x;
    if (tid < 128) pl[tid] = pooled[g * 128 + tid];
    __syncthreads();
    float s = bh1[tid];
#pragma unroll 16
    for (int k = 0; k < 128; k++) s = fmaf(pl[k], Wh1[k * 512 + tid], s);
    float gl = 0.5f * s * (1.0f + erff(s * 0.70710678118654752f));
    float p = gl * Wh2[tid];
    for (int off = 32; off >= 1; off >>= 1) p += __shfl_down(p, off);
    if ((tid & 63) == 0) red[tid >> 6] = p;
    __syncthreads();
    if (tid == 0) {
        float tot = 0.f;
        for (int i = 0; i < 8; i++) tot += red[i];
        out[g] = tot + bh2[0];
    }
}

extern "C" void kernel_launch(void* const* d_in, const int* in_sizes, int n_in,
                              void* d_out, int out_size, void* d_ws, size_t ws_size,
                              hipStream_t stream) {
    const float* x = (const float*)d_in[0];
    const int* ei = (const int*)d_in[1];
    const float* eattr = (const float*)d_in[2];
    const int* batch = (const int*)d_in[3];
    const float* Wv = (const float*)d_in[4];
    const float* We = (const float*)d_in[5];
    const float* convW = (const float*)d_in[6];
    const float* convB = (const float*)d_in[7];
    const float* Wh1 = (const float*)d_in[8];
    const float* bh1 = (const float*)d_in[9];
    const float* Wh2 = (const float*)d_in[10];
    const float* bh2 = (const float*)d_in[11];
    float* out = (float*)d_out;

    const int* src = ei;
    const int* dst = ei + N_EDGES;

    // workspace carve-up (256B aligned) — total ~68 MB
    char* w = (char*)d_ws;
    size_t off = 0;
    auto alloc = [&](size_t bytes) -> char* {
        char* p = w + off;
        off += (bytes + 255) & ~(size_t)255;
        return p;
    };
    float* bufA = (float*)alloc((size_t)N_NODES * DCH * 4);   // h
    float* bufB = (float*)alloc((size_t)N_NODES * DCH * 4);   // v
    int* deg = (int*)alloc((size_t)(N_NODES + 1) * 4);
    int* rowp = (int*)alloc((size_t)(N_NODES + 1) * 4);
    int* cursor = (int*)alloc((size_t)(N_NODES + 1) * 4);
    int* srcp = (int*)alloc((size_t)N_EDGES * 4);
    float* eattrp = (float*)alloc((size_t)N_EDGES * 4 * 4);
    int* gs = (int*)alloc((size_t)(N_GRAPHS + 1) * 4);
    float* pooled = (float*)alloc((size_t)N_GRAPHS * DCH * 4);
    (void)ws_size; (void)n_in; (void)in_sizes; (void)out_size;

    hipMemsetAsync(deg, 0, (size_t)(N_NODES + 1) * 4, stream);

    hist_kernel<<<N_EDGES / 256, 256, 0, stream>>>(dst, deg);
    scan_kernel<<<1, 1024, 0, stream>>>(deg, rowp, cursor);
    scatter_kernel<<<N_EDGES / 256, 256, 0, stream>>>(src, dst, eattr, cursor, srcp, eattrp);
    h0_kernel<<<N_NODES * 64 / 256, 256, 0, stream>>>(x, Wv, bufA);
    bounds_kernel<<<(N_NODES + 255) / 256, 256, 0, stream>>>(batch, gs);

    float* hcur = bufA;
    float* vbuf = bufB;
    for (int layer = 0; layer < N_LAYERS; layer++) {
        aggr_kernel<<<N_NODES / 4, 256, 0, stream>>>(hcur, eattrp, rowp, srcp, We, vbuf);
        gemm_kernel<<<(N_NODES + 31) / 32, 256, 0, stream>>>(
            vbuf, convW + (size_t)layer * DCH * DCH, convB + (size_t)layer * DCH, hcur);
        float* t = hcur; hcur = vbuf; vbuf = t;  // gemm wrote new h into vbuf
    }

    pool_kernel<<<N_GRAPHS, 128, 0, stream>>>(hcur, gs, pooled);
    mlp_kernel<<<N_GRAPHS, 512, 0, stream>>>(pooled, Wh1, bh1, Wh2, bh2, out);
}

// Round 3
// 1271.005 us; speedup vs baseline: 1.0750x; 1.0750x over previous
//
#include <hip/hip_runtime.h>
#include <math.h>

#define N_NODES 50000
#define N_EDGES 800000
#define DCH 128
#define N_LAYERS 9
#define N_GRAPHS 256
#define EPSF 1e-5f
#define NCHUNK 196  // ceil(50000/256)

// ---------------- CSR build ----------------
__global__ void hist_kernel(const int* __restrict__ dst, int* __restrict__ deg) {
    int t = blockIdx.x * 256 + threadIdx.x;   // grid covers exactly N_EDGES
    atomicAdd(&deg[dst[t]], 1);
}

__global__ __launch_bounds__(256) void chunksum_kernel(const int* __restrict__ deg,
                                                       int* __restrict__ csum) {
    int t = threadIdx.x;
    int i = blockIdx.x * 256 + t;
    int v = (i < N_NODES) ? deg[i] : 0;
    __shared__ int sh[4];
    for (int off = 32; off >= 1; off >>= 1) v += __shfl_down(v, off);
    if ((t & 63) == 0) sh[t >> 6] = v;
    __syncthreads();
    if (t == 0) csum[blockIdx.x] = sh[0] + sh[1] + sh[2] + sh[3];
}

__global__ __launch_bounds__(256) void chunkscan_kernel(const int* __restrict__ csum,
                                                        int* __restrict__ coff) {
    __shared__ int sh[256];
    int t = threadIdx.x;
    sh[t] = (t < NCHUNK) ? csum[t] : 0;
    __syncthreads();
    for (int off = 1; off < 256; off <<= 1) {
        int v = (t >= off) ? sh[t - off] : 0;
        __syncthreads();
        sh[t] += v;
        __syncthreads();
    }
    if (t < NCHUNK) coff[t] = t ? sh[t - 1] : 0;  // exclusive
}

__global__ __launch_bounds__(256) void applyscan_kernel(const int* __restrict__ deg,
                                                        const int* __restrict__ coff,
                                                        int* __restrict__ rowp,
                                                        int* __restrict__ cursor) {
    __shared__ int sh[256];
    int t = threadIdx.x;
    int i = blockIdx.x * 256 + t;
    int d = (i < N_NODES) ? deg[i] : 0;
    sh[t] = d;
    __syncthreads();
    for (int off = 1; off < 256; off <<= 1) {
        int v = (t >= off) ? sh[t - off] : 0;
        __syncthreads();
        sh[t] += v;
        __syncthreads();
    }
    int excl = coff[blockIdx.x] + (t ? sh[t - 1] : 0);
    if (i < N_NODES) {
        rowp[i] = excl;
        cursor[i] = excl;
    }
    if (i == N_NODES - 1) rowp[N_NODES] = N_EDGES;
}

__global__ void scatter_kernel(const int* __restrict__ src, const int* __restrict__ dst,
                               const float* __restrict__ eattr,
                               int* __restrict__ cursor, int* __restrict__ srcp,
                               float* __restrict__ eattrp) {
    int t = blockIdx.x * 256 + threadIdx.x;   // grid covers exactly N_EDGES
    int d = dst[t];
    int p = atomicAdd(&cursor[d], 1);
    srcp[p] = src[t];
    ((float4*)eattrp)[p] = ((const float4*)eattr)[t];
}

// ---------------- h0 = x @ Wv ----------------
__global__ void h0_kernel(const float* __restrict__ x, const float* __restrict__ Wv,
                          float* __restrict__ h) {
    int t = blockIdx.x * 256 + threadIdx.x;
    int n = t >> 6, l = t & 63;
    const float* xr = x + n * 13;
    float s0 = 0.f, s1 = 0.f;
#pragma unroll
    for (int j = 0; j < 13; j++) {
        float xv = xr[j];
        s0 = fmaf(xv, Wv[j * 128 + 2 * l], s0);
        s1 = fmaf(xv, Wv[j * 128 + 2 * l + 1], s1);
    }
    ((float2*)h)[n * 64 + l] = make_float2(s0, s1);
}

// ---------------- per-layer aggregation ----------------
// v = (1+eps)*h + sum_{edges into n} relu(h[src] + edge_attr[e] @ We)
// One wave per node; lane l covers channels 2l, 2l+1. Edge metadata reads are
// wave-uniform (broadcast); no shfls. Unroll-by-2 for two gathers in flight.
__global__ __launch_bounds__(256) void aggr_kernel(const float* __restrict__ h,
                                                   const float* __restrict__ eattrp,
                                                   const int* __restrict__ rowp,
                                                   const int* __restrict__ srcp,
                                                   const float* __restrict__ We,
                                                   float* __restrict__ v) {
    int n = blockIdx.x * 4 + (threadIdx.x >> 6);
    int l = threadIdx.x & 63;
    float w00 = We[0 * 128 + 2 * l], w01 = We[0 * 128 + 2 * l + 1];
    float w10 = We[1 * 128 + 2 * l], w11 = We[1 * 128 + 2 * l + 1];
    float w20 = We[2 * 128 + 2 * l], w21 = We[2 * 128 + 2 * l + 1];
    float w30 = We[3 * 128 + 2 * l], w31 = We[3 * 128 + 2 * l + 1];
    int start = rowp[n], end = rowp[n + 1];
    float a0 = 0.f, a1 = 0.f;
    const float2* h2 = (const float2*)h;
    const float4* e4 = (const float4*)eattrp;
    int e = start;
    for (; e + 2 <= end; e += 2) {
        int s0 = srcp[e], s1 = srcp[e + 1];
        float4 av0 = e4[e], av1 = e4[e + 1];
        float2 hv0 = h2[(size_t)s0 * 64 + l];
        float2 hv1 = h2[(size_t)s1 * 64 + l];
        float p0 = fmaf(av0.x, w00, fmaf(av0.y, w10, fmaf(av0.z, w20, av0.w * w30)));
        float p1 = fmaf(av0.x, w01, fmaf(av0.y, w11, fmaf(av0.z, w21, av0.w * w31)));
        float q0 = fmaf(av1.x, w00, fmaf(av1.y, w10, fmaf(av1.z, w20, av1.w * w30)));
        float q1 = fmaf(av1.x, w01, fmaf(av1.y, w11, fmaf(av1.z, w21, av1.w * w31)));
        a0 += fmaxf(hv0.x + p0, 0.f) + fmaxf(hv1.x + q0, 0.f);
        a1 += fmaxf(hv0.y + p1, 0.f) + fmaxf(hv1.y + q1, 0.f);
    }
    if (e < end) {
        int s0 = srcp[e];
        float4 av0 = e4[e];
        float2 hv0 = h2[(size_t)s0 * 64 + l];
        float p0 = fmaf(av0.x, w00, fmaf(av0.y, w10, fmaf(av0.z, w20, av0.w * w30)));
        float p1 = fmaf(av0.x, w01, fmaf(av0.y, w11, fmaf(av0.z, w21, av0.w * w31)));
        a0 += fmaxf(hv0.x + p0, 0.f);
        a1 += fmaxf(hv0.y + p1, 0.f);
    }
    float2 hn = h2[(size_t)n * 64 + l];
    ((float2*)v)[(size_t)n * 64 + l] =
        make_float2(fmaf(hn.x, 1.f + EPSF, a0), fmaf(hn.y, 1.f + EPSF, a1));
}

// ---------------- per-layer GEMM: v <- relu(v @ W + b) + hin  (in-place on v) ----------------
__global__ __launch_bounds__(256) void gemm_kernel(float* __restrict__ v,
                                                   const float* __restrict__ W,
                                                   const float* __restrict__ b,
                                                   const float* __restrict__ hin) {
    __shared__ float4 vl4[32 * 32];  // 32 nodes x 128 ch = 16 KiB
    int tid = threadIdx.x;
    int row0 = blockIdx.x * 32;
    const float4* vg4 = (const float4*)v;
#pragma unroll
    for (int i = 0; i < 4; i++) {
        int idx = tid + i * 256;  // 0..1023
        int r = idx >> 5;
        int node = row0 + r;
        float4 val = make_float4(0.f, 0.f, 0.f, 0.f);
        if (node < N_NODES) val = vg4[(size_t)node * 32 + (idx & 31)];
        vl4[idx] = val;
    }
    __syncthreads();
    int cg = tid & 31;   // 4 channels: 4*cg..4*cg+3
    int mg = tid >> 5;   // 8 groups x 4 nodes
    float4 acc[4];
#pragma unroll
    for (int m = 0; m < 4; m++) acc[m] = make_float4(0.f, 0.f, 0.f, 0.f);
    const float4* Wg4 = (const float4*)W;
#pragma unroll 4
    for (int k = 0; k < 128; k += 4) {
        float4 w0 = Wg4[k * 32 + cg];
        float4 w1 = Wg4[(k + 1) * 32 + cg];
        float4 w2 = Wg4[(k + 2) * 32 + cg];
        float4 w3 = Wg4[(k + 3) * 32 + cg];
#pragma unroll
        for (int m = 0; m < 4; m++) {
            float4 vv = vl4[(mg * 4 + m) * 32 + (k >> 2)];
            acc[m].x += w0.x * vv.x + w1.x * vv.y + w2.x * vv.z + w3.x * vv.w;
            acc[m].y += w0.y * vv.x + w1.y * vv.y + w2.y * vv.z + w3.y * vv.w;
            acc[m].z += w0.z * vv.x + w1.z * vv.y + w2.z * vv.z + w3.z * vv.w;
            acc[m].w += w0.w * vv.x + w1.w * vv.y + w2.w * vv.z + w3.w * vv.w;
        }
    }
    float4 bb = ((const float4*)b)[cg];
    const float4* h4 = (const float4*)hin;
    float4* o4 = (float4*)v;
#pragma unroll
    for (int m = 0; m < 4; m++) {
        int node = row0 + mg * 4 + m;
        if (node < N_NODES) {
            float4 hh = h4[(size_t)node * 32 + cg];
            float4 r;
            r.x = fmaxf(acc[m].x + bb.x, 0.f) + hh.x;
            r.y = fmaxf(acc[m].y + bb.y, 0.f) + hh.y;
            r.z = fmaxf(acc[m].z + bb.z, 0.f) + hh.z;
            r.w = fmaxf(acc[m].w + bb.w, 0.f) + hh.w;
            o4[(size_t)node * 32 + cg] = r;
        }
    }
}

// ---------------- graph boundaries (batch is sorted) ----------------
__global__ void bounds_kernel(const int* __restrict__ batch, int* __restrict__ gs) {
    int n = blockIdx.x * 256 + threadIdx.x;
    if (n >= N_NODES) return;
    int bcur = batch[n];
    int prev = (n == 0) ? -1 : batch[n - 1];
    for (int g = prev + 1; g <= bcur; g++) gs[g] = n;
    if (n == N_NODES - 1) {
        for (int g = bcur + 1; g <= N_GRAPHS; g++) gs[g] = N_NODES;
    }
}

// ---------------- mean pool (block per graph, no atomics) ----------------
__global__ __launch_bounds__(128) void pool_kernel(const float* __restrict__ h,
                                                   const int* __restrict__ gs,
                                                   float* __restrict__ pooled) {
    int g = blockIdx.x;
    int c = threadIdx.x;
    int s = gs[g], e = gs[g + 1];
    float acc = 0.f;
    for (int n = s; n < e; n++) acc += h[(size_t)n * 128 + c];
    pooled[g * 128 + c] = acc / fmaxf((float)(e - s), 1.0f);
}

// ---------------- MLP head ----------------
__global__ __launch_bounds__(512) void mlp_kernel(const float* __restrict__ pooled,
                                                  const float* __restrict__ Wh1,
                                                  const float* __restrict__ bh1,
                                                  const float* __restrict__ Wh2,
                                                  const float* __restrict__ bh2,
                                                  float* __restrict__ out) {
    int g = blockIdx.x;
    __shared__ float pl[128];
    __shared__ float red[8];
    int tid = threadIdx.x;
    if (tid < 128) pl[tid] = pooled[g * 128 + tid];
    __syncthreads();
    float s = bh1[tid];
#pragma unroll 16
    for (int k = 0; k < 128; k++) s = fmaf(pl[k], Wh1[k * 512 + tid], s);
    float gl = 0.5f * s * (1.0f + erff(s * 0.70710678118654752f));
    float p = gl * Wh2[tid];
    for (int off = 32; off >= 1; off >>= 1) p += __shfl_down(p, off);
    if ((tid & 63) == 0) red[tid >> 6] = p;
    __syncthreads();
    if (tid == 0) {
        float tot = 0.f;
        for (int i = 0; i < 8; i++) tot += red[i];
        out[g] = tot + bh2[0];
    }
}

extern "C" void kernel_launch(void* const* d_in, const int* in_sizes, int n_in,
                              void* d_out, int out_size, void* d_ws, size_t ws_size,
                              hipStream_t stream) {
    const float* x = (const float*)d_in[0];
    const int* ei = (const int*)d_in[1];
    const float* eattr = (const float*)d_in[2];
    const int* batch = (const int*)d_in[3];
    const float* Wv = (const float*)d_in[4];
    const float* We = (const float*)d_in[5];
    const float* convW = (const float*)d_in[6];
    const float* convB = (const float*)d_in[7];
    const float* Wh1 = (const float*)d_in[8];
    const float* bh1 = (const float*)d_in[9];
    const float* Wh2 = (const float*)d_in[10];
    const float* bh2 = (const float*)d_in[11];
    float* out = (float*)d_out;

    const int* src = ei;
    const int* dst = ei + N_EDGES;

    // workspace carve-up (256B aligned) — total ~68 MB
    char* w = (char*)d_ws;
    size_t off = 0;
    auto alloc = [&](size_t bytes) -> char* {
        char* p = w + off;
        off += (bytes + 255) & ~(size_t)255;
        return p;
    };
    float* bufA = (float*)alloc((size_t)N_NODES * DCH * 4);   // h
    float* bufB = (float*)alloc((size_t)N_NODES * DCH * 4);   // v
    int* deg = (int*)alloc((size_t)(N_NODES + 1) * 4);
    int* rowp = (int*)alloc((size_t)(N_NODES + 1) * 4);
    int* cursor = (int*)alloc((size_t)(N_NODES + 1) * 4);
    int* csum = (int*)alloc((size_t)NCHUNK * 4);
    int* coff = (int*)alloc((size_t)NCHUNK * 4);
    int* srcp = (int*)alloc((size_t)N_EDGES * 4);
    float* eattrp = (float*)alloc((size_t)N_EDGES * 4 * 4);
    int* gs = (int*)alloc((size_t)(N_GRAPHS + 1) * 4);
    float* pooled = (float*)alloc((size_t)N_GRAPHS * DCH * 4);
    (void)ws_size; (void)n_in; (void)in_sizes; (void)out_size;

    hipMemsetAsync(deg, 0, (size_t)(N_NODES + 1) * 4, stream);

    hist_kernel<<<N_EDGES / 256, 256, 0, stream>>>(dst, deg);
    chunksum_kernel<<<NCHUNK, 256, 0, stream>>>(deg, csum);
    chunkscan_kernel<<<1, 256, 0, stream>>>(csum, coff);
    applyscan_kernel<<<NCHUNK, 256, 0, stream>>>(deg, coff, rowp, cursor);
    scatter_kernel<<<N_EDGES / 256, 256, 0, stream>>>(src, dst, eattr, cursor, srcp, eattrp);
    h0_kernel<<<N_NODES * 64 / 256, 256, 0, stream>>>(x, Wv, bufA);
    bounds_kernel<<<(N_NODES + 255) / 256, 256, 0, stream>>>(batch, gs);

    float* hcur = bufA;
    float* vbuf = bufB;
    for (int layer = 0; layer < N_LAYERS; layer++) {
        aggr_kernel<<<N_NODES / 4, 256, 0, stream>>>(hcur, eattrp, rowp, srcp, We, vbuf);
        gemm_kernel<<<(N_NODES + 31) / 32, 256, 0, stream>>>(
            vbuf, convW + (size_t)layer * DCH * DCH, convB + (size_t)layer * DCH, hcur);
        float* t = hcur; hcur = vbuf; vbuf = t;  // gemm wrote new h into vbuf
    }

    pool_kernel<<<N_GRAPHS, 128, 0, stream>>>(hcur, gs, pooled);
    mlp_kernel<<<N_GRAPHS, 512, 0, stream>>>(pooled, Wh1, bh1, Wh2, bh2, out);
}

// Round 4
// 1082.388 us; speedup vs baseline: 1.2623x; 1.1743x over previous
//
#include <hip/hip_runtime.h>
#include <math.h>

#define N_NODES 50000
#define N_EDGES 800000
#define DCH 128
#define N_LAYERS 9
#define N_GRAPHS 256
#define EPSF 1e-5f
#define NCHUNK 196  // ceil(50000/256)

static __device__ __forceinline__ unsigned short f2bf(float f) {
    unsigned int u = __float_as_uint(f);
    unsigned int r = (u + 0x7fffu + ((u >> 16) & 1u)) >> 16;  // RNE
    return (unsigned short)r;
}
static __device__ __forceinline__ unsigned int pack_bf2(float a, float b) {
    return (unsigned int)f2bf(a) | ((unsigned int)f2bf(b) << 16);
}

// ---------------- CSR build ----------------
__global__ void hist_kernel(const int* __restrict__ dst, int* __restrict__ deg) {
    int t = blockIdx.x * 256 + threadIdx.x;   // grid covers exactly N_EDGES
    atomicAdd(&deg[dst[t]], 1);
}

__global__ __launch_bounds__(256) void chunksum_kernel(const int* __restrict__ deg,
                                                       int* __restrict__ csum) {
    int t = threadIdx.x;
    int i = blockIdx.x * 256 + t;
    int v = (i < N_NODES) ? deg[i] : 0;
    __shared__ int sh[4];
    for (int off = 32; off >= 1; off >>= 1) v += __shfl_down(v, off);
    if ((t & 63) == 0) sh[t >> 6] = v;
    __syncthreads();
    if (t == 0) csum[blockIdx.x] = sh[0] + sh[1] + sh[2] + sh[3];
}

__global__ __launch_bounds__(256) void chunkscan_kernel(const int* __restrict__ csum,
                                                        int* __restrict__ coff) {
    __shared__ int sh[256];
    int t = threadIdx.x;
    sh[t] = (t < NCHUNK) ? csum[t] : 0;
    __syncthreads();
    for (int off = 1; off < 256; off <<= 1) {
        int v = (t >= off) ? sh[t - off] : 0;
        __syncthreads();
        sh[t] += v;
        __syncthreads();
    }
    if (t < NCHUNK) coff[t] = t ? sh[t - 1] : 0;  // exclusive
}

__global__ __launch_bounds__(256) void applyscan_kernel(const int* __restrict__ deg,
                                                        const int* __restrict__ coff,
                                                        int* __restrict__ rowp,
                                                        int* __restrict__ cursor) {
    __shared__ int sh[256];
    int t = threadIdx.x;
    int i = blockIdx.x * 256 + t;
    int d = (i < N_NODES) ? deg[i] : 0;
    sh[t] = d;
    __syncthreads();
    for (int off = 1; off < 256; off <<= 1) {
        int v = (t >= off) ? sh[t - off] : 0;
        __syncthreads();
        sh[t] += v;
        __syncthreads();
    }
    int excl = coff[blockIdx.x] + (t ? sh[t - 1] : 0);
    if (i < N_NODES) {
        rowp[i] = excl;
        cursor[i] = excl;
    }
    if (i == N_NODES - 1) rowp[N_NODES] = N_EDGES;
}

__global__ void scatter_kernel(const int* __restrict__ src, const int* __restrict__ dst,
                               const float* __restrict__ eattr,
                               int* __restrict__ cursor, int* __restrict__ srcp,
                               float* __restrict__ eattrp) {
    int t = blockIdx.x * 256 + threadIdx.x;   // grid covers exactly N_EDGES
    int d = dst[t];
    int p = atomicAdd(&cursor[d], 1);
    srcp[p] = src[t];
    ((float4*)eattrp)[p] = ((const float4*)eattr)[t];
}

// ---------------- h0 = x @ Wv (writes fp32 h + bf16 shadow) ----------------
__global__ void h0_kernel(const float* __restrict__ x, const float* __restrict__ Wv,
                          float* __restrict__ h, unsigned int* __restrict__ hbf) {
    int t = blockIdx.x * 256 + threadIdx.x;
    int n = t >> 6, l = t & 63;
    const float* xr = x + n * 13;
    float s0 = 0.f, s1 = 0.f;
#pragma unroll
    for (int j = 0; j < 13; j++) {
        float xv = xr[j];
        s0 = fmaf(xv, Wv[j * 128 + 2 * l], s0);
        s1 = fmaf(xv, Wv[j * 128 + 2 * l + 1], s1);
    }
    ((float2*)h)[n * 64 + l] = make_float2(s0, s1);
    hbf[n * 64 + l] = pack_bf2(s0, s1);
}

// ---------------- per-layer aggregation ----------------
// v = (1+eps)*h + sum_{edges into n} relu(hbf[src] + edge_attr[e] @ We)
// One wave per node; lane l covers channels 2l, 2l+1 (one bf16x2 dword per
// lane per edge). Manual unroll-4: 4 independent gathers in flight.
__global__ __launch_bounds__(256) void aggr_kernel(const float* __restrict__ h,
                                                   const unsigned int* __restrict__ hbf,
                                                   const float* __restrict__ eattrp,
                                                   const int* __restrict__ rowp,
                                                   const int* __restrict__ srcp,
                                                   const float* __restrict__ We,
                                                   float* __restrict__ v) {
    int n = blockIdx.x * 4 + (threadIdx.x >> 6);
    int l = threadIdx.x & 63;
    float w00 = We[0 * 128 + 2 * l], w01 = We[0 * 128 + 2 * l + 1];
    float w10 = We[1 * 128 + 2 * l], w11 = We[1 * 128 + 2 * l + 1];
    float w20 = We[2 * 128 + 2 * l], w21 = We[2 * 128 + 2 * l + 1];
    float w30 = We[3 * 128 + 2 * l], w31 = We[3 * 128 + 2 * l + 1];
    int start = rowp[n], end = rowp[n + 1];
    float a0 = 0.f, a1 = 0.f;
    const float4* e4 = (const float4*)eattrp;
    int e = start;
    for (; e + 4 <= end; e += 4) {
        int s0 = srcp[e], s1 = srcp[e + 1], s2 = srcp[e + 2], s3 = srcp[e + 3];
        unsigned int u0 = hbf[(size_t)s0 * 64 + l];
        unsigned int u1 = hbf[(size_t)s1 * 64 + l];
        unsigned int u2 = hbf[(size_t)s2 * 64 + l];
        unsigned int u3 = hbf[(size_t)s3 * 64 + l];
        float4 av0 = e4[e], av1 = e4[e + 1], av2 = e4[e + 2], av3 = e4[e + 3];
        float p0 = fmaf(av0.x, w00, fmaf(av0.y, w10, fmaf(av0.z, w20, av0.w * w30)));
        float p1 = fmaf(av0.x, w01, fmaf(av0.y, w11, fmaf(av0.z, w21, av0.w * w31)));
        float q0 = fmaf(av1.x, w00, fmaf(av1.y, w10, fmaf(av1.z, w20, av1.w * w30)));
        float q1 = fmaf(av1.x, w01, fmaf(av1.y, w11, fmaf(av1.z, w21, av1.w * w31)));
        float r0 = fmaf(av2.x, w00, fmaf(av2.y, w10, fmaf(av2.z, w20, av2.w * w30)));
        float r1 = fmaf(av2.x, w01, fmaf(av2.y, w11, fmaf(av2.z, w21, av2.w * w31)));
        float t0 = fmaf(av3.x, w00, fmaf(av3.y, w10, fmaf(av3.z, w20, av3.w * w30)));
        float t1 = fmaf(av3.x, w01, fmaf(av3.y, w11, fmaf(av3.z, w21, av3.w * w31)));
        a0 += fmaxf(__uint_as_float(u0 << 16) + p0, 0.f);
        a1 += fmaxf(__uint_as_float(u0 & 0xffff0000u) + p1, 0.f);
        a0 += fmaxf(__uint_as_float(u1 << 16) + q0, 0.f);
        a1 += fmaxf(__uint_as_float(u1 & 0xffff0000u) + q1, 0.f);
        a0 += fmaxf(__uint_as_float(u2 << 16) + r0, 0.f);
        a1 += fmaxf(__uint_as_float(u2 & 0xffff0000u) + r1, 0.f);
        a0 += fmaxf(__uint_as_float(u3 << 16) + t0, 0.f);
        a1 += fmaxf(__uint_as_float(u3 & 0xffff0000u) + t1, 0.f);
    }
    for (; e < end; e++) {
        int s0 = srcp[e];
        unsigned int u0 = hbf[(size_t)s0 * 64 + l];
        float4 av0 = e4[e];
        float p0 = fmaf(av0.x, w00, fmaf(av0.y, w10, fmaf(av0.z, w20, av0.w * w30)));
        float p1 = fmaf(av0.x, w01, fmaf(av0.y, w11, fmaf(av0.z, w21, av0.w * w31)));
        a0 += fmaxf(__uint_as_float(u0 << 16) + p0, 0.f);
        a1 += fmaxf(__uint_as_float(u0 & 0xffff0000u) + p1, 0.f);
    }
    const float2* h2 = (const float2*)h;
    float2 hn = h2[(size_t)n * 64 + l];
    ((float2*)v)[(size_t)n * 64 + l] =
        make_float2(fmaf(hn.x, 1.f + EPSF, a0), fmaf(hn.y, 1.f + EPSF, a1));
}

// ---------------- per-layer GEMM: v <- relu(v @ W + b) + hin  (in-place on v) ----------------
// Also writes the bf16 shadow of the new h.
__global__ __launch_bounds__(256) void gemm_kernel(float* __restrict__ v,
                                                   const float* __restrict__ W,
                                                   const float* __restrict__ b,
                                                   const float* __restrict__ hin,
                                                   unsigned int* __restrict__ hbf) {
    __shared__ float4 vl4[32 * 32];  // 32 nodes x 128 ch = 16 KiB
    int tid = threadIdx.x;
    int row0 = blockIdx.x * 32;
    const float4* vg4 = (const float4*)v;
#pragma unroll
    for (int i = 0; i < 4; i++) {
        int idx = tid + i * 256;  // 0..1023
        int r = idx >> 5;
        int node = row0 + r;
        float4 val = make_float4(0.f, 0.f, 0.f, 0.f);
        if (node < N_NODES) val = vg4[(size_t)node * 32 + (idx & 31)];
        vl4[idx] = val;
    }
    __syncthreads();
    int cg = tid & 31;   // 4 channels: 4*cg..4*cg+3
    int mg = tid >> 5;   // 8 groups x 4 nodes
    float4 acc[4];
#pragma unroll
    for (int m = 0; m < 4; m++) acc[m] = make_float4(0.f, 0.f, 0.f, 0.f);
    const float4* Wg4 = (const float4*)W;
#pragma unroll 4
    for (int k = 0; k < 128; k += 4) {
        float4 w0 = Wg4[k * 32 + cg];
        float4 w1 = Wg4[(k + 1) * 32 + cg];
        float4 w2 = Wg4[(k + 2) * 32 + cg];
        float4 w3 = Wg4[(k + 3) * 32 + cg];
#pragma unroll
        for (int m = 0; m < 4; m++) {
            float4 vv = vl4[(mg * 4 + m) * 32 + (k >> 2)];
            acc[m].x += w0.x * vv.x + w1.x * vv.y + w2.x * vv.z + w3.x * vv.w;
            acc[m].y += w0.y * vv.x + w1.y * vv.y + w2.y * vv.z + w3.y * vv.w;
            acc[m].z += w0.z * vv.x + w1.z * vv.y + w2.z * vv.z + w3.z * vv.w;
            acc[m].w += w0.w * vv.x + w1.w * vv.y + w2.w * vv.z + w3.w * vv.w;
        }
    }
    float4 bb = ((const float4*)b)[cg];
    const float4* h4 = (const float4*)hin;
    float4* o4 = (float4*)v;
#pragma unroll
    for (int m = 0; m < 4; m++) {
        int node = row0 + mg * 4 + m;
        if (node < N_NODES) {
            float4 hh = h4[(size_t)node * 32 + cg];
            float4 r;
            r.x = fmaxf(acc[m].x + bb.x, 0.f) + hh.x;
            r.y = fmaxf(acc[m].y + bb.y, 0.f) + hh.y;
            r.z = fmaxf(acc[m].z + bb.z, 0.f) + hh.z;
            r.w = fmaxf(acc[m].w + bb.w, 0.f) + hh.w;
            o4[(size_t)node * 32 + cg] = r;
            uint2 pk;
            pk.x = pack_bf2(r.x, r.y);
            pk.y = pack_bf2(r.z, r.w);
            ((uint2*)hbf)[(size_t)node * 32 + cg] = pk;
        }
    }
}

// ---------------- graph boundaries (batch is sorted) ----------------
__global__ void bounds_kernel(const int* __restrict__ batch, int* __restrict__ gs) {
    int n = blockIdx.x * 256 + threadIdx.x;
    if (n >= N_NODES) return;
    int bcur = batch[n];
    int prev = (n == 0) ? -1 : batch[n - 1];
    for (int g = prev + 1; g <= bcur; g++) gs[g] = n;
    if (n == N_NODES - 1) {
        for (int g = bcur + 1; g <= N_GRAPHS; g++) gs[g] = N_NODES;
    }
}

// ---------------- mean pool (block per graph, no atomics) ----------------
__global__ __launch_bounds__(128) void pool_kernel(const float* __restrict__ h,
                                                   const int* __restrict__ gs,
                                                   float* __restrict__ pooled) {
    int g = blockIdx.x;
    int c = threadIdx.x;
    int s = gs[g], e = gs[g + 1];
    float acc = 0.f;
    for (int n = s; n < e; n++) acc += h[(size_t)n * 128 + c];
    pooled[g * 128 + c] = acc / fmaxf((float)(e - s), 1.0f);
}

// ---------------- MLP head ----------------
__global__ __launch_bounds__(512) void mlp_kernel(const float* __restrict__ pooled,
                                                  const float* __restrict__ Wh1,
                                                  const float* __restrict__ bh1,
                                                  const float* __restrict__ Wh2,
                                                  const float* __restrict__ bh2,
                                                  float* __restrict__ out) {
    int g = blockIdx.x;
    __shared__ float pl[128];
    __shared__ float red[8];
    int tid = threadIdx.x;
    if (tid < 128) pl[tid] = pooled[g * 128 + tid];
    __syncthreads();
    float s = bh1[tid];
#pragma unroll 16
    for (int k = 0; k < 128; k++) s = fmaf(pl[k], Wh1[k * 512 + tid], s);
    float gl = 0.5f * s * (1.0f + erff(s * 0.70710678118654752f));
    float p = gl * Wh2[tid];
    for (int off = 32; off >= 1; off >>= 1) p += __shfl_down(p, off);
    if ((tid & 63) == 0) red[tid >> 6] = p;
    __syncthreads();
    if (tid == 0) {
        float tot = 0.f;
        for (int i = 0; i < 8; i++) tot += red[i];
        out[g] = tot + bh2[0];
    }
}

extern "C" void kernel_launch(void* const* d_in, const int* in_sizes, int n_in,
                              void* d_out, int out_size, void* d_ws, size_t ws_size,
                              hipStream_t stream) {
    const float* x = (const float*)d_in[0];
    const int* ei = (const int*)d_in[1];
    const float* eattr = (const float*)d_in[2];
    const int* batch = (const int*)d_in[3];
    const float* Wv = (const float*)d_in[4];
    const float* We = (const float*)d_in[5];
    const float* convW = (const float*)d_in[6];
    const float* convB = (const float*)d_in[7];
    const float* Wh1 = (const float*)d_in[8];
    const float* bh1 = (const float*)d_in[9];
    const float* Wh2 = (const float*)d_in[10];
    const float* bh2 = (const float*)d_in[11];
    float* out = (float*)d_out;

    const int* src = ei;
    const int* dst = ei + N_EDGES;

    // workspace carve-up (256B aligned) — total ~81 MB
    char* w = (char*)d_ws;
    size_t off = 0;
    auto alloc = [&](size_t bytes) -> char* {
        char* p = w + off;
        off += (bytes + 255) & ~(size_t)255;
        return p;
    };
    float* bufA = (float*)alloc((size_t)N_NODES * DCH * 4);   // h
    float* bufB = (float*)alloc((size_t)N_NODES * DCH * 4);   // v
    unsigned int* hbf = (unsigned int*)alloc((size_t)N_NODES * 64 * 4);  // bf16 shadow
    int* deg = (int*)alloc((size_t)(N_NODES + 1) * 4);
    int* rowp = (int*)alloc((size_t)(N_NODES + 1) * 4);
    int* cursor = (int*)alloc((size_t)(N_NODES + 1) * 4);
    int* csum = (int*)alloc((size_t)NCHUNK * 4);
    int* coff = (int*)alloc((size_t)NCHUNK * 4);
    int* srcp = (int*)alloc((size_t)N_EDGES * 4);
    float* eattrp = (float*)alloc((size_t)N_EDGES * 4 * 4);
    int* gs = (int*)alloc((size_t)(N_GRAPHS + 1) * 4);
    float* pooled = (float*)alloc((size_t)N_GRAPHS * DCH * 4);
    (void)ws_size; (void)n_in; (void)in_sizes; (void)out_size;

    hipMemsetAsync(deg, 0, (size_t)(N_NODES + 1) * 4, stream);

    hist_kernel<<<N_EDGES / 256, 256, 0, stream>>>(dst, deg);
    chunksum_kernel<<<NCHUNK, 256, 0, stream>>>(deg, csum);
    chunkscan_kernel<<<1, 256, 0, stream>>>(csum, coff);
    applyscan_kernel<<<NCHUNK, 256, 0, stream>>>(deg, coff, rowp, cursor);
    scatter_kernel<<<N_EDGES / 256, 256, 0, stream>>>(src, dst, eattr, cursor, srcp, eattrp);
    h0_kernel<<<N_NODES * 64 / 256, 256, 0, stream>>>(x, Wv, bufA, hbf);
    bounds_kernel<<<(N_NODES + 255) / 256, 256, 0, stream>>>(batch, gs);

    float* hcur = bufA;
    float* vbuf = bufB;
    for (int layer = 0; layer < N_LAYERS; layer++) {
        aggr_kernel<<<N_NODES / 4, 256, 0, stream>>>(hcur, hbf, eattrp, rowp, srcp, We, vbuf);
        gemm_kernel<<<(N_NODES + 31) / 32, 256, 0, stream>>>(
            vbuf, convW + (size_t)layer * DCH * DCH, convB + (size_t)layer * DCH, hcur, hbf);
        float* t = hcur; hcur = vbuf; vbuf = t;  // gemm wrote new h into vbuf
    }

    pool_kernel<<<N_GRAPHS, 128, 0, stream>>>(hcur, gs, pooled);
    mlp_kernel<<<N_GRAPHS, 512, 0, stream>>>(pooled, Wh1, bh1, Wh2, bh2, out);
}

// Round 5
// 904.996 us; speedup vs baseline: 1.5098x; 1.1960x over previous
//
#include <hip/hip_runtime.h>
#include <math.h>

#define N_NODES 50000
#define N_EDGES 800000
#define DCH 128
#define N_LAYERS 9
#define N_GRAPHS 256
#define EPSF 1e-5f
#define NCHUNK 196  // ceil(50000/256)

typedef __attribute__((ext_vector_type(8))) short short8;   // 8 bf16 = 4 VGPRs
typedef __attribute__((ext_vector_type(4))) float floatx4;

static __device__ __forceinline__ unsigned short f2bf(float f) {
    unsigned int u = __float_as_uint(f);
    unsigned int r = (u + 0x7fffu + ((u >> 16) & 1u)) >> 16;  // RNE
    return (unsigned short)r;
}
static __device__ __forceinline__ unsigned int pack_bf2(float a, float b) {
    return (unsigned int)f2bf(a) | ((unsigned int)f2bf(b) << 16);
}

// ---------------- CSR build ----------------
__global__ void hist_kernel(const int* __restrict__ dst, int* __restrict__ deg) {
    int t = blockIdx.x * 256 + threadIdx.x;   // grid covers exactly N_EDGES
    atomicAdd(&deg[dst[t]], 1);
}

__global__ __launch_bounds__(256) void chunksum_kernel(const int* __restrict__ deg,
                                                       int* __restrict__ csum) {
    int t = threadIdx.x;
    int i = blockIdx.x * 256 + t;
    int v = (i < N_NODES) ? deg[i] : 0;
    __shared__ int sh[4];
    for (int off = 32; off >= 1; off >>= 1) v += __shfl_down(v, off);
    if ((t & 63) == 0) sh[t >> 6] = v;
    __syncthreads();
    if (t == 0) csum[blockIdx.x] = sh[0] + sh[1] + sh[2] + sh[3];
}

__global__ __launch_bounds__(256) void chunkscan_kernel(const int* __restrict__ csum,
                                                        int* __restrict__ coff) {
    __shared__ int sh[256];
    int t = threadIdx.x;
    sh[t] = (t < NCHUNK) ? csum[t] : 0;
    __syncthreads();
    for (int off = 1; off < 256; off <<= 1) {
        int v = (t >= off) ? sh[t - off] : 0;
        __syncthreads();
        sh[t] += v;
        __syncthreads();
    }
    if (t < NCHUNK) coff[t] = t ? sh[t - 1] : 0;  // exclusive
}

__global__ __launch_bounds__(256) void applyscan_kernel(const int* __restrict__ deg,
                                                        const int* __restrict__ coff,
                                                        int* __restrict__ rowp,
                                                        int* __restrict__ cursor) {
    __shared__ int sh[256];
    int t = threadIdx.x;
    int i = blockIdx.x * 256 + t;
    int d = (i < N_NODES) ? deg[i] : 0;
    sh[t] = d;
    __syncthreads();
    for (int off = 1; off < 256; off <<= 1) {
        int v = (t >= off) ? sh[t - off] : 0;
        __syncthreads();
        sh[t] += v;
        __syncthreads();
    }
    int excl = coff[blockIdx.x] + (t ? sh[t - 1] : 0);
    if (i < N_NODES) {
        rowp[i] = excl;
        cursor[i] = excl;
    }
    if (i == N_NODES - 1) rowp[N_NODES] = N_EDGES;
}

__global__ void scatter_kernel(const int* __restrict__ src, const int* __restrict__ dst,
                               const float* __restrict__ eattr,
                               int* __restrict__ cursor, int* __restrict__ srcp,
                               float* __restrict__ eattrp) {
    int t = blockIdx.x * 256 + threadIdx.x;   // grid covers exactly N_EDGES
    int d = dst[t];
    int p = atomicAdd(&cursor[d], 1);
    srcp[p] = src[t];
    ((float4*)eattrp)[p] = ((const float4*)eattr)[t];
}

// ---------------- conv weights -> MFMA B-fragment layout, bf16 ----------------
// Per layer: 8 jt x 4 kt tiles; per tile: 64 lanes x 8 bf16 (16 B contiguous).
// B frag: lane holds B[k = kt*32 + (lane>>4)*8 + j][n = jt*16 + (lane&15)], j=0..7.
__global__ __launch_bounds__(256) void wconv_kernel(const float* __restrict__ convW,
                                                    uint4* __restrict__ wb) {
    int tid = blockIdx.x * 256 + threadIdx.x;  // 72 blocks * 256 = 18432 exactly
    int lane = tid & 63;
    int t = (tid >> 6) & 31;
    int layer = tid >> 11;
    int jt = t >> 2, kt = t & 3;
    int quad = lane >> 4, col = lane & 15;
    const float* Wl = convW + (size_t)layer * DCH * DCH;
    int kbase = kt * 32 + quad * 8;
    int ch = jt * 16 + col;
    unsigned int d0 = pack_bf2(Wl[(kbase + 0) * DCH + ch], Wl[(kbase + 1) * DCH + ch]);
    unsigned int d1 = pack_bf2(Wl[(kbase + 2) * DCH + ch], Wl[(kbase + 3) * DCH + ch]);
    unsigned int d2 = pack_bf2(Wl[(kbase + 4) * DCH + ch], Wl[(kbase + 5) * DCH + ch]);
    unsigned int d3 = pack_bf2(Wl[(kbase + 6) * DCH + ch], Wl[(kbase + 7) * DCH + ch]);
    wb[tid] = make_uint4(d0, d1, d2, d3);
}

// ---------------- h0 = x @ Wv (writes fp32 h + bf16 shadow) ----------------
__global__ void h0_kernel(const float* __restrict__ x, const float* __restrict__ Wv,
                          float* __restrict__ h, unsigned int* __restrict__ hbf) {
    int t = blockIdx.x * 256 + threadIdx.x;
    int n = t >> 6, l = t & 63;
    const float* xr = x + n * 13;
    float s0 = 0.f, s1 = 0.f;
#pragma unroll
    for (int j = 0; j < 13; j++) {
        float xv = xr[j];
        s0 = fmaf(xv, Wv[j * 128 + 2 * l], s0);
        s1 = fmaf(xv, Wv[j * 128 + 2 * l + 1], s1);
    }
    ((float2*)h)[n * 64 + l] = make_float2(s0, s1);
    hbf[n * 64 + l] = pack_bf2(s0, s1);
}

// ---------------- per-layer aggregation ----------------
// vbf = bf16( (1+eps)*h + sum_{edges into n} relu(hbf[src] + edge_attr[e] @ We) )
__global__ __launch_bounds__(256) void aggr_kernel(const float* __restrict__ h,
                                                   const unsigned int* __restrict__ hbf,
                                                   const float* __restrict__ eattrp,
                                                   const int* __restrict__ rowp,
                                                   const int* __restrict__ srcp,
                                                   const float* __restrict__ We,
                                                   unsigned int* __restrict__ vbf) {
    int n = blockIdx.x * 4 + (threadIdx.x >> 6);
    int l = threadIdx.x & 63;
    float w00 = We[0 * 128 + 2 * l], w01 = We[0 * 128 + 2 * l + 1];
    float w10 = We[1 * 128 + 2 * l], w11 = We[1 * 128 + 2 * l + 1];
    float w20 = We[2 * 128 + 2 * l], w21 = We[2 * 128 + 2 * l + 1];
    float w30 = We[3 * 128 + 2 * l], w31 = We[3 * 128 + 2 * l + 1];
    int start = rowp[n], end = rowp[n + 1];
    float a0 = 0.f, a1 = 0.f;
    const float4* e4 = (const float4*)eattrp;
    int e = start;
    for (; e + 4 <= end; e += 4) {
        int s0 = srcp[e], s1 = srcp[e + 1], s2 = srcp[e + 2], s3 = srcp[e + 3];
        unsigned int u0 = hbf[(size_t)s0 * 64 + l];
        unsigned int u1 = hbf[(size_t)s1 * 64 + l];
        unsigned int u2 = hbf[(size_t)s2 * 64 + l];
        unsigned int u3 = hbf[(size_t)s3 * 64 + l];
        float4 av0 = e4[e], av1 = e4[e + 1], av2 = e4[e + 2], av3 = e4[e + 3];
        float p0 = fmaf(av0.x, w00, fmaf(av0.y, w10, fmaf(av0.z, w20, av0.w * w30)));
        float p1 = fmaf(av0.x, w01, fmaf(av0.y, w11, fmaf(av0.z, w21, av0.w * w31)));
        float q0 = fmaf(av1.x, w00, fmaf(av1.y, w10, fmaf(av1.z, w20, av1.w * w30)));
        float q1 = fmaf(av1.x, w01, fmaf(av1.y, w11, fmaf(av1.z, w21, av1.w * w31)));
        float r0 = fmaf(av2.x, w00, fmaf(av2.y, w10, fmaf(av2.z, w20, av2.w * w30)));
        float r1 = fmaf(av2.x, w01, fmaf(av2.y, w11, fmaf(av2.z, w21, av2.w * w31)));
        float t0 = fmaf(av3.x, w00, fmaf(av3.y, w10, fmaf(av3.z, w20, av3.w * w30)));
        float t1 = fmaf(av3.x, w01, fmaf(av3.y, w11, fmaf(av3.z, w21, av3.w * w31)));
        a0 += fmaxf(__uint_as_float(u0 << 16) + p0, 0.f);
        a1 += fmaxf(__uint_as_float(u0 & 0xffff0000u) + p1, 0.f);
        a0 += fmaxf(__uint_as_float(u1 << 16) + q0, 0.f);
        a1 += fmaxf(__uint_as_float(u1 & 0xffff0000u) + q1, 0.f);
        a0 += fmaxf(__uint_as_float(u2 << 16) + r0, 0.f);
        a1 += fmaxf(__uint_as_float(u2 & 0xffff0000u) + r1, 0.f);
        a0 += fmaxf(__uint_as_float(u3 << 16) + t0, 0.f);
        a1 += fmaxf(__uint_as_float(u3 & 0xffff0000u) + t1, 0.f);
    }
    for (; e < end; e++) {
        int s0 = srcp[e];
        unsigned int u0 = hbf[(size_t)s0 * 64 + l];
        float4 av0 = e4[e];
        float p0 = fmaf(av0.x, w00, fmaf(av0.y, w10, fmaf(av0.z, w20, av0.w * w30)));
        float p1 = fmaf(av0.x, w01, fmaf(av0.y, w11, fmaf(av0.z, w21, av0.w * w31)));
        a0 += fmaxf(__uint_as_float(u0 << 16) + p0, 0.f);
        a1 += fmaxf(__uint_as_float(u0 & 0xffff0000u) + p1, 0.f);
    }
    const float2* h2 = (const float2*)h;
    float2 hn = h2[(size_t)n * 64 + l];
    float vx = fmaf(hn.x, 1.f + EPSF, a0);
    float vy = fmaf(hn.y, 1.f + EPSF, a1);
    vbf[(size_t)n * 64 + l] = pack_bf2(vx, vy);
}

// ---------------- per-layer GEMM via MFMA ----------------
// hout = relu(vbf @ W + b) + hin ; also writes bf16 shadow hbf.
// One wave per 16 nodes. A frag: lane -> node n0+(lane&15), k=(lane>>4)*8+kt*32 (16B
// contiguous in row-major vbf). B frag: prepacked by wconv_kernel. D: lane,reg r ->
// node n0+(lane>>4)*4+r, ch jt*16+(lane&15).
__global__ __launch_bounds__(256) void gemm_kernel(const unsigned short* __restrict__ vbf,
                                                   const short8* __restrict__ wbL,
                                                   const float* __restrict__ b,
                                                   const float* __restrict__ hin,
                                                   float* __restrict__ hout,
                                                   unsigned short* __restrict__ hbf) {
    int lane = threadIdx.x & 63;
    int wave = threadIdx.x >> 6;
    int n0 = (blockIdx.x * 4 + wave) * 16;
    int col = lane & 15, quad = lane >> 4;
    int arow = n0 + col;
    int arow_c = (arow < N_NODES) ? arow : (N_NODES - 1);
    const short8* va8 = (const short8*)(vbf + (size_t)arow_c * DCH);
    short8 a[4];
#pragma unroll
    for (int kt = 0; kt < 4; kt++) a[kt] = va8[kt * 4 + quad];
    int nodeb = n0 + quad * 4;
#pragma unroll
    for (int jt = 0; jt < 8; jt++) {
        floatx4 acc = {0.f, 0.f, 0.f, 0.f};
#pragma unroll
        for (int kt = 0; kt < 4; kt++) {
            short8 bf = wbL[(jt * 4 + kt) * 64 + lane];
            acc = __builtin_amdgcn_mfma_f32_16x16x32_bf16(a[kt], bf, acc, 0, 0, 0);
        }
        float bv = b[jt * 16 + col];
#pragma unroll
        for (int r = 0; r < 4; r++) {
            int nd = nodeb + r;
            if (nd < N_NODES) {
                size_t idx = (size_t)nd * DCH + jt * 16 + col;
                float o = fmaxf(acc[r] + bv, 0.f) + hin[idx];
                hout[idx] = o;
                hbf[idx] = f2bf(o);
            }
        }
    }
}

// ---------------- graph boundaries (batch is sorted) ----------------
__global__ void bounds_kernel(const int* __restrict__ batch, int* __restrict__ gs) {
    int n = blockIdx.x * 256 + threadIdx.x;
    if (n >= N_NODES) return;
    int bcur = batch[n];
    int prev = (n == 0) ? -1 : batch[n - 1];
    for (int g = prev + 1; g <= bcur; g++) gs[g] = n;
    if (n == N_NODES - 1) {
        for (int g = bcur + 1; g <= N_GRAPHS; g++) gs[g] = N_NODES;
    }
}

// ---------------- mean pool (block per graph, no atomics) ----------------
__global__ __launch_bounds__(128) void pool_kernel(const float* __restrict__ h,
                                                   const int* __restrict__ gs,
                                                   float* __restrict__ pooled) {
    int g = blockIdx.x;
    int c = threadIdx.x;
    int s = gs[g], e = gs[g + 1];
    float acc = 0.f;
    for (int n = s; n < e; n++) acc += h[(size_t)n * 128 + c];
    pooled[g * 128 + c] = acc / fmaxf((float)(e - s), 1.0f);
}

// ---------------- MLP head ----------------
__global__ __launch_bounds__(512) void mlp_kernel(const float* __restrict__ pooled,
                                                  const float* __restrict__ Wh1,
                                                  const float* __restrict__ bh1,
                                                  const float* __restrict__ Wh2,
                                                  const float* __restrict__ bh2,
                                                  float* __restrict__ out) {
    int g = blockIdx.x;
    __shared__ float pl[128];
    __shared__ float red[8];
    int tid = threadIdx.x;
    if (tid < 128) pl[tid] = pooled[g * 128 + tid];
    __syncthreads();
    float s = bh1[tid];
#pragma unroll 16
    for (int k = 0; k < 128; k++) s = fmaf(pl[k], Wh1[k * 512 + tid], s);
    float gl = 0.5f * s * (1.0f + erff(s * 0.70710678118654752f));
    float p = gl * Wh2[tid];
    for (int off = 32; off >= 1; off >>= 1) p += __shfl_down(p, off);
    if ((tid & 63) == 0) red[tid >> 6] = p;
    __syncthreads();
    if (tid == 0) {
        float tot = 0.f;
        for (int i = 0; i < 8; i++) tot += red[i];
        out[g] = tot + bh2[0];
    }
}

extern "C" void kernel_launch(void* const* d_in, const int* in_sizes, int n_in,
                              void* d_out, int out_size, void* d_ws, size_t ws_size,
                              hipStream_t stream) {
    const float* x = (const float*)d_in[0];
    const int* ei = (const int*)d_in[1];
    const float* eattr = (const float*)d_in[2];
    const int* batch = (const int*)d_in[3];
    const float* Wv = (const float*)d_in[4];
    const float* We = (const float*)d_in[5];
    const float* convW = (const float*)d_in[6];
    const float* convB = (const float*)d_in[7];
    const float* Wh1 = (const float*)d_in[8];
    const float* bh1 = (const float*)d_in[9];
    const float* Wh2 = (const float*)d_in[10];
    const float* bh2 = (const float*)d_in[11];
    float* out = (float*)d_out;

    const int* src = ei;
    const int* dst = ei + N_EDGES;

    // workspace carve-up (256B aligned) — total ~94 MB
    char* w = (char*)d_ws;
    size_t off = 0;
    auto alloc = [&](size_t bytes) -> char* {
        char* p = w + off;
        off += (bytes + 255) & ~(size_t)255;
        return p;
    };
    float* bufA = (float*)alloc((size_t)N_NODES * DCH * 4);              // h (ping)
    float* bufB = (float*)alloc((size_t)N_NODES * DCH * 4);              // h (pong)
    unsigned int* hbf = (unsigned int*)alloc((size_t)N_NODES * 64 * 4);  // bf16 h shadow
    unsigned int* vbf = (unsigned int*)alloc((size_t)N_NODES * 64 * 4);  // bf16 v
    uint4* wb = (uint4*)alloc((size_t)N_LAYERS * 32 * 64 * 16);          // MFMA W frags
    int* deg = (int*)alloc((size_t)(N_NODES + 1) * 4);
    int* rowp = (int*)alloc((size_t)(N_NODES + 1) * 4);
    int* cursor = (int*)alloc((size_t)(N_NODES + 1) * 4);
    int* csum = (int*)alloc((size_t)NCHUNK * 4);
    int* coff = (int*)alloc((size_t)NCHUNK * 4);
    int* srcp = (int*)alloc((size_t)N_EDGES * 4);
    float* eattrp = (float*)alloc((size_t)N_EDGES * 4 * 4);
    int* gs = (int*)alloc((size_t)(N_GRAPHS + 1) * 4);
    float* pooled = (float*)alloc((size_t)N_GRAPHS * DCH * 4);
    (void)ws_size; (void)n_in; (void)in_sizes; (void)out_size;

    hipMemsetAsync(deg, 0, (size_t)(N_NODES + 1) * 4, stream);

    hist_kernel<<<N_EDGES / 256, 256, 0, stream>>>(dst, deg);
    chunksum_kernel<<<NCHUNK, 256, 0, stream>>>(deg, csum);
    chunkscan_kernel<<<1, 256, 0, stream>>>(csum, coff);
    applyscan_kernel<<<NCHUNK, 256, 0, stream>>>(deg, coff, rowp, cursor);
    scatter_kernel<<<N_EDGES / 256, 256, 0, stream>>>(src, dst, eattr, cursor, srcp, eattrp);
    wconv_kernel<<<72, 256, 0, stream>>>(convW, wb);
    h0_kernel<<<N_NODES * 64 / 256, 256, 0, stream>>>(x, Wv, bufA, hbf);
    bounds_kernel<<<(N_NODES + 255) / 256, 256, 0, stream>>>(batch, gs);

    float* hcur = bufA;
    float* hnext = bufB;
    for (int layer = 0; layer < N_LAYERS; layer++) {
        aggr_kernel<<<N_NODES / 4, 256, 0, stream>>>(hcur, hbf, eattrp, rowp, srcp, We, vbf);
        gemm_kernel<<<(N_NODES + 63) / 64, 256, 0, stream>>>(
            (const unsigned short*)vbf, (const short8*)(wb + (size_t)layer * 2048),
            convB + (size_t)layer * DCH, hcur, hnext, (unsigned short*)hbf);
        float* t = hcur; hcur = hnext; hnext = t;
    }

    pool_kernel<<<N_GRAPHS, 128, 0, stream>>>(hcur, gs, pooled);
    mlp_kernel<<<N_GRAPHS, 512, 0, stream>>>(pooled, Wh1, bh1, Wh2, bh2, out);
}

// Round 6
// 826.922 us; speedup vs baseline: 1.6523x; 1.0944x over previous
//
#include <hip/hip_runtime.h>
#include <math.h>

#define N_NODES 50000
#define N_EDGES 800000
#define DCH 128
#define N_LAYERS 9
#define N_GRAPHS 256
#define EPSF 1e-5f
#define NCHUNK 196  // ceil(50000/256)

typedef __attribute__((ext_vector_type(8))) short short8;   // 8 bf16 = 4 VGPRs
typedef __attribute__((ext_vector_type(4))) float floatx4;

static __device__ __forceinline__ unsigned short f2bf(float f) {
    unsigned int u = __float_as_uint(f);
    unsigned int r = (u + 0x7fffu + ((u >> 16) & 1u)) >> 16;  // RNE
    return (unsigned short)r;
}
static __device__ __forceinline__ unsigned int pack_bf2(float a, float b) {
    return (unsigned int)f2bf(a) | ((unsigned int)f2bf(b) << 16);
}
static __device__ __forceinline__ float bflo(unsigned int u) { return __uint_as_float(u << 16); }
static __device__ __forceinline__ float bfhi(unsigned int u) { return __uint_as_float(u & 0xffff0000u); }

// ---------------- CSR build ----------------
__global__ void hist_kernel(const int* __restrict__ dst, int* __restrict__ deg) {
    int t = blockIdx.x * 256 + threadIdx.x;   // grid covers exactly N_EDGES
    atomicAdd(&deg[dst[t]], 1);
}

__global__ __launch_bounds__(256) void chunksum_kernel(const int* __restrict__ deg,
                                                       int* __restrict__ csum) {
    int t = threadIdx.x;
    int i = blockIdx.x * 256 + t;
    int v = (i < N_NODES) ? deg[i] : 0;
    __shared__ int sh[4];
    for (int off = 32; off >= 1; off >>= 1) v += __shfl_down(v, off);
    if ((t & 63) == 0) sh[t >> 6] = v;
    __syncthreads();
    if (t == 0) csum[blockIdx.x] = sh[0] + sh[1] + sh[2] + sh[3];
}

__global__ __launch_bounds__(256) void chunkscan_kernel(const int* __restrict__ csum,
                                                        int* __restrict__ coff) {
    __shared__ int sh[256];
    int t = threadIdx.x;
    sh[t] = (t < NCHUNK) ? csum[t] : 0;
    __syncthreads();
    for (int off = 1; off < 256; off <<= 1) {
        int v = (t >= off) ? sh[t - off] : 0;
        __syncthreads();
        sh[t] += v;
        __syncthreads();
    }
    if (t < NCHUNK) coff[t] = t ? sh[t - 1] : 0;  // exclusive
}

__global__ __launch_bounds__(256) void applyscan_kernel(const int* __restrict__ deg,
                                                        const int* __restrict__ coff,
                                                        int* __restrict__ rowp,
                                                        int* __restrict__ cursor) {
    __shared__ int sh[256];
    int t = threadIdx.x;
    int i = blockIdx.x * 256 + t;
    int d = (i < N_NODES) ? deg[i] : 0;
    sh[t] = d;
    __syncthreads();
    for (int off = 1; off < 256; off <<= 1) {
        int v = (t >= off) ? sh[t - off] : 0;
        __syncthreads();
        sh[t] += v;
        __syncthreads();
    }
    int excl = coff[blockIdx.x] + (t ? sh[t - 1] : 0);
    if (i < N_NODES) {
        rowp[i] = excl;
        cursor[i] = excl;
    }
    if (i == N_NODES - 1) rowp[N_NODES] = N_EDGES;
}

// one 16B record per edge: {src, bf16x2(a.x,a.y), bf16x2(a.z,a.w), pad}
__global__ void scatter_kernel(const int* __restrict__ src, const int* __restrict__ dst,
                               const float* __restrict__ eattr,
                               int* __restrict__ cursor, uint4* __restrict__ erec) {
    int t = blockIdx.x * 256 + threadIdx.x;   // grid covers exactly N_EDGES
    int d = dst[t];
    int p = atomicAdd(&cursor[d], 1);
    float4 a = ((const float4*)eattr)[t];
    erec[p] = make_uint4((unsigned int)src[t], pack_bf2(a.x, a.y), pack_bf2(a.z, a.w), 0u);
}

// ---------------- conv weights -> MFMA B-fragment layout, bf16 ----------------
__global__ __launch_bounds__(256) void wconv_kernel(const float* __restrict__ convW,
                                                    uint4* __restrict__ wb) {
    int tid = blockIdx.x * 256 + threadIdx.x;  // 72 blocks * 256 = 18432 exactly
    int lane = tid & 63;
    int t = (tid >> 6) & 31;
    int layer = tid >> 11;
    int jt = t >> 2, kt = t & 3;
    int quad = lane >> 4, col = lane & 15;
    const float* Wl = convW + (size_t)layer * DCH * DCH;
    int kbase = kt * 32 + quad * 8;
    int ch = jt * 16 + col;
    unsigned int d0 = pack_bf2(Wl[(kbase + 0) * DCH + ch], Wl[(kbase + 1) * DCH + ch]);
    unsigned int d1 = pack_bf2(Wl[(kbase + 2) * DCH + ch], Wl[(kbase + 3) * DCH + ch]);
    unsigned int d2 = pack_bf2(Wl[(kbase + 4) * DCH + ch], Wl[(kbase + 5) * DCH + ch]);
    unsigned int d3 = pack_bf2(Wl[(kbase + 6) * DCH + ch], Wl[(kbase + 7) * DCH + ch]);
    wb[tid] = make_uint4(d0, d1, d2, d3);
}

// ---------------- h0 = x @ Wv (writes fp32 h + bf16 shadow) ----------------
__global__ void h0_kernel(const float* __restrict__ x, const float* __restrict__ Wv,
                          float* __restrict__ h, unsigned int* __restrict__ hbf) {
    int t = blockIdx.x * 256 + threadIdx.x;
    int n = t >> 6, l = t & 63;
    const float* xr = x + n * 13;
    float s0 = 0.f, s1 = 0.f;
#pragma unroll
    for (int j = 0; j < 13; j++) {
        float xv = xr[j];
        s0 = fmaf(xv, Wv[j * 128 + 2 * l], s0);
        s1 = fmaf(xv, Wv[j * 128 + 2 * l + 1], s1);
    }
    ((float2*)h)[n * 64 + l] = make_float2(s0, s1);
    hbf[n * 64 + l] = pack_bf2(s0, s1);
}

// ---------------- per-layer aggregation ----------------
// vbf = bf16( (1+eps)*h + sum_{edges into n} relu(hbf[src] + eattr[e] @ We) )
__global__ __launch_bounds__(256) void aggr_kernel(const float* __restrict__ h,
                                                   const unsigned int* __restrict__ hbf,
                                                   const uint4* __restrict__ erec,
                                                   const int* __restrict__ rowp,
                                                   const float* __restrict__ We,
                                                   unsigned int* __restrict__ vbf) {
    int n = blockIdx.x * 4 + (threadIdx.x >> 6);
    int l = threadIdx.x & 63;
    float w00 = We[0 * 128 + 2 * l], w01 = We[0 * 128 + 2 * l + 1];
    float w10 = We[1 * 128 + 2 * l], w11 = We[1 * 128 + 2 * l + 1];
    float w20 = We[2 * 128 + 2 * l], w21 = We[2 * 128 + 2 * l + 1];
    float w30 = We[3 * 128 + 2 * l], w31 = We[3 * 128 + 2 * l + 1];
    int start = rowp[n], end = rowp[n + 1];
    float a0 = 0.f, a1 = 0.f;
    int e = start;
    for (; e + 4 <= end; e += 4) {
        uint4 r0 = erec[e], r1 = erec[e + 1], r2 = erec[e + 2], r3 = erec[e + 3];
        unsigned int u0 = hbf[(size_t)r0.x * 64 + l];
        unsigned int u1 = hbf[(size_t)r1.x * 64 + l];
        unsigned int u2 = hbf[(size_t)r2.x * 64 + l];
        unsigned int u3 = hbf[(size_t)r3.x * 64 + l];
        float p0 = fmaf(bflo(r0.y), w00, fmaf(bfhi(r0.y), w10, fmaf(bflo(r0.z), w20, bfhi(r0.z) * w30)));
        float p1 = fmaf(bflo(r0.y), w01, fmaf(bfhi(r0.y), w11, fmaf(bflo(r0.z), w21, bfhi(r0.z) * w31)));
        float q0 = fmaf(bflo(r1.y), w00, fmaf(bfhi(r1.y), w10, fmaf(bflo(r1.z), w20, bfhi(r1.z) * w30)));
        float q1 = fmaf(bflo(r1.y), w01, fmaf(bfhi(r1.y), w11, fmaf(bflo(r1.z), w21, bfhi(r1.z) * w31)));
        float s0 = fmaf(bflo(r2.y), w00, fmaf(bfhi(r2.y), w10, fmaf(bflo(r2.z), w20, bfhi(r2.z) * w30)));
        float s1 = fmaf(bflo(r2.y), w01, fmaf(bfhi(r2.y), w11, fmaf(bflo(r2.z), w21, bfhi(r2.z) * w31)));
        float t0 = fmaf(bflo(r3.y), w00, fmaf(bfhi(r3.y), w10, fmaf(bflo(r3.z), w20, bfhi(r3.z) * w30)));
        float t1 = fmaf(bflo(r3.y), w01, fmaf(bfhi(r3.y), w11, fmaf(bflo(r3.z), w21, bfhi(r3.z) * w31)));
        a0 += fmaxf(bflo(u0) + p0, 0.f);
        a1 += fmaxf(bfhi(u0) + p1, 0.f);
        a0 += fmaxf(bflo(u1) + q0, 0.f);
        a1 += fmaxf(bfhi(u1) + q1, 0.f);
        a0 += fmaxf(bflo(u2) + s0, 0.f);
        a1 += fmaxf(bfhi(u2) + s1, 0.f);
        a0 += fmaxf(bflo(u3) + t0, 0.f);
        a1 += fmaxf(bfhi(u3) + t1, 0.f);
    }
    for (; e < end; e++) {
        uint4 r0 = erec[e];
        unsigned int u0 = hbf[(size_t)r0.x * 64 + l];
        float p0 = fmaf(bflo(r0.y), w00, fmaf(bfhi(r0.y), w10, fmaf(bflo(r0.z), w20, bfhi(r0.z) * w30)));
        float p1 = fmaf(bflo(r0.y), w01, fmaf(bfhi(r0.y), w11, fmaf(bflo(r0.z), w21, bfhi(r0.z) * w31)));
        a0 += fmaxf(bflo(u0) + p0, 0.f);
        a1 += fmaxf(bfhi(u0) + p1, 0.f);
    }
    const float2* h2 = (const float2*)h;
    float2 hn = h2[(size_t)n * 64 + l];
    float vx = fmaf(hn.x, 1.f + EPSF, a0);
    float vy = fmaf(hn.y, 1.f + EPSF, a1);
    vbf[(size_t)n * 64 + l] = pack_bf2(vx, vy);
}

// ---------------- per-layer GEMM via MFMA, LDS-transposed epilogue ----------------
// hout = relu(vbf @ W + b) + hin ; also writes bf16 shadow hbf.
// 4 waves/block, 16 nodes/wave (64 nodes/block). MFMA D -> LDS (padded) ->
// fully coalesced float4/uint2 epilogue.
#define OLP 132  // padded row: 128 + 4
__global__ __launch_bounds__(256) void gemm_kernel(const unsigned short* __restrict__ vbf,
                                                   const short8* __restrict__ wbL,
                                                   const float* __restrict__ b,
                                                   const float* __restrict__ hin,
                                                   float* __restrict__ hout,
                                                   unsigned short* __restrict__ hbf) {
    __shared__ float ol[64 * OLP];  // 33 KiB
    int tid = threadIdx.x;
    int lane = tid & 63;
    int wave = tid >> 6;
    int nb = blockIdx.x * 64;
    int n0 = nb + wave * 16;
    int col = lane & 15, quad = lane >> 4;
    int arow = n0 + col;
    int arow_c = (arow < N_NODES) ? arow : (N_NODES - 1);
    const short8* va8 = (const short8*)(vbf + (size_t)arow_c * DCH);
    short8 a[4];
#pragma unroll
    for (int kt = 0; kt < 4; kt++) a[kt] = va8[kt * 4 + quad];
#pragma unroll
    for (int jt = 0; jt < 8; jt++) {
        floatx4 acc = {0.f, 0.f, 0.f, 0.f};
#pragma unroll
        for (int kt = 0; kt < 4; kt++) {
            short8 bf = wbL[(jt * 4 + kt) * 64 + lane];
            acc = __builtin_amdgcn_mfma_f32_16x16x32_bf16(a[kt], bf, acc, 0, 0, 0);
        }
        float bv = b[jt * 16 + col];
#pragma unroll
        for (int r = 0; r < 4; r++) {
            ol[(wave * 16 + quad * 4 + r) * OLP + jt * 16 + col] = fmaxf(acc[r] + bv, 0.f);
        }
    }
    __syncthreads();
    const float4* h4 = (const float4*)hin;
    float4* o4 = (float4*)hout;
    uint2* b2 = (uint2*)hbf;
#pragma unroll
    for (int i = 0; i < 8; i++) {
        int idx = i * 256 + tid;            // 0..2047
        int nl = idx >> 5, c4 = idx & 31;   // node-local, float4-chunk
        int node = nb + nl;
        if (node < N_NODES) {
            const float* row = ol + nl * OLP + c4 * 4;
            float4 hh = h4[(size_t)node * 32 + c4];
            float4 r;
            r.x = row[0] + hh.x;
            r.y = row[1] + hh.y;
            r.z = row[2] + hh.z;
            r.w = row[3] + hh.w;
            o4[(size_t)node * 32 + c4] = r;
            b2[(size_t)node * 32 + c4] = make_uint2(pack_bf2(r.x, r.y), pack_bf2(r.z, r.w));
        }
    }
}

// ---------------- graph boundaries (batch is sorted) ----------------
__global__ void bounds_kernel(const int* __restrict__ batch, int* __restrict__ gs) {
    int n = blockIdx.x * 256 + threadIdx.x;
    if (n >= N_NODES) return;
    int bcur = batch[n];
    int prev = (n == 0) ? -1 : batch[n - 1];
    for (int g = prev + 1; g <= bcur; g++) gs[g] = n;
    if (n == N_NODES - 1) {
        for (int g = bcur + 1; g <= N_GRAPHS; g++) gs[g] = N_NODES;
    }
}

// ---------------- mean pool (block per graph, no atomics) ----------------
__global__ __launch_bounds__(128) void pool_kernel(const float* __restrict__ h,
                                                   const int* __restrict__ gs,
                                                   float* __restrict__ pooled) {
    int g = blockIdx.x;
    int c = threadIdx.x;
    int s = gs[g], e = gs[g + 1];
    float acc = 0.f;
    for (int n = s; n < e; n++) acc += h[(size_t)n * 128 + c];
    pooled[g * 128 + c] = acc / fmaxf((float)(e - s), 1.0f);
}

// ---------------- MLP head ----------------
__global__ __launch_bounds__(512) void mlp_kernel(const float* __restrict__ pooled,
                                                  const float* __restrict__ Wh1,
                                                  const float* __restrict__ bh1,
                                                  const float* __restrict__ Wh2,
                                                  const float* __restrict__ bh2,
                                                  float* __restrict__ out) {
    int g = blockIdx.x;
    __shared__ float pl[128];
    __shared__ float red[8];
    int tid = threadIdx.x;
    if (tid < 128) pl[tid] = pooled[g * 128 + tid];
    __syncthreads();
    float s = bh1[tid];
#pragma unroll 16
    for (int k = 0; k < 128; k++) s = fmaf(pl[k], Wh1[k * 512 + tid], s);
    float gl = 0.5f * s * (1.0f + erff(s * 0.70710678118654752f));
    float p = gl * Wh2[tid];
    for (int off = 32; off >= 1; off >>= 1) p += __shfl_down(p, off);
    if ((tid & 63) == 0) red[tid >> 6] = p;
    __syncthreads();
    if (tid == 0) {
        float tot = 0.f;
        for (int i = 0; i < 8; i++) tot += red[i];
        out[g] = tot + bh2[0];
    }
}

extern "C" void kernel_launch(void* const* d_in, const int* in_sizes, int n_in,
                              void* d_out, int out_size, void* d_ws, size_t ws_size,
                              hipStream_t stream) {
    const float* x = (const float*)d_in[0];
    const int* ei = (const int*)d_in[1];
    const float* eattr = (const float*)d_in[2];
    const int* batch = (const int*)d_in[3];
    const float* Wv = (const float*)d_in[4];
    const float* We = (const float*)d_in[5];
    const float* convW = (const float*)d_in[6];
    const float* convB = (const float*)d_in[7];
    const float* Wh1 = (const float*)d_in[8];
    const float* bh1 = (const float*)d_in[9];
    const float* Wh2 = (const float*)d_in[10];
    const float* bh2 = (const float*)d_in[11];
    float* out = (float*)d_out;

    const int* src = ei;
    const int* dst = ei + N_EDGES;

    // workspace carve-up (256B aligned) — total ~90 MB
    char* w = (char*)d_ws;
    size_t off = 0;
    auto alloc = [&](size_t bytes) -> char* {
        char* p = w + off;
        off += (bytes + 255) & ~(size_t)255;
        return p;
    };
    float* bufA = (float*)alloc((size_t)N_NODES * DCH * 4);              // h (ping)
    float* bufB = (float*)alloc((size_t)N_NODES * DCH * 4);              // h (pong)
    unsigned int* hbf = (unsigned int*)alloc((size_t)N_NODES * 64 * 4);  // bf16 h shadow
    unsigned int* vbf = (unsigned int*)alloc((size_t)N_NODES * 64 * 4);  // bf16 v
    uint4* wb = (uint4*)alloc((size_t)N_LAYERS * 32 * 64 * 16);          // MFMA W frags
    int* deg = (int*)alloc((size_t)(N_NODES + 1) * 4);
    int* rowp = (int*)alloc((size_t)(N_NODES + 1) * 4);
    int* cursor = (int*)alloc((size_t)(N_NODES + 1) * 4);
    int* csum = (int*)alloc((size_t)NCHUNK * 4);
    int* coff = (int*)alloc((size_t)NCHUNK * 4);
    uint4* erec = (uint4*)alloc((size_t)N_EDGES * 16);
    int* gs = (int*)alloc((size_t)(N_GRAPHS + 1) * 4);
    float* pooled = (float*)alloc((size_t)N_GRAPHS * DCH * 4);
    (void)ws_size; (void)n_in; (void)in_sizes; (void)out_size;

    hipMemsetAsync(deg, 0, (size_t)(N_NODES + 1) * 4, stream);

    hist_kernel<<<N_EDGES / 256, 256, 0, stream>>>(dst, deg);
    chunksum_kernel<<<NCHUNK, 256, 0, stream>>>(deg, csum);
    chunkscan_kernel<<<1, 256, 0, stream>>>(csum, coff);
    applyscan_kernel<<<NCHUNK, 256, 0, stream>>>(deg, coff, rowp, cursor);
    scatter_kernel<<<N_EDGES / 256, 256, 0, stream>>>(src, dst, eattr, cursor, erec);
    wconv_kernel<<<72, 256, 0, stream>>>(convW, wb);
    h0_kernel<<<N_NODES * 64 / 256, 256, 0, stream>>>(x, Wv, bufA, hbf);
    bounds_kernel<<<(N_NODES + 255) / 256, 256, 0, stream>>>(batch, gs);

    float* hcur = bufA;
    float* hnext = bufB;
    for (int layer = 0; layer < N_LAYERS; layer++) {
        aggr_kernel<<<N_NODES / 4, 256, 0, stream>>>(hcur, hbf, erec, rowp, We, vbf);
        gemm_kernel<<<(N_NODES + 63) / 64, 256, 0, stream>>>(
            (const unsigned short*)vbf, (const short8*)(wb + (size_t)layer * 2048),
            convB + (size_t)layer * DCH, hcur, hnext, (unsigned short*)hbf);
        float* t = hcur; hcur = hnext; hnext = t;
    }

    pool_kernel<<<N_GRAPHS, 128, 0, stream>>>(hcur, gs, pooled);
    mlp_kernel<<<N_GRAPHS, 512, 0, stream>>>(pooled, Wh1, bh1, Wh2, bh2, out);
}

// Round 7
// 780.683 us; speedup vs baseline: 1.7502x; 1.0592x over previous
//
#include <hip/hip_runtime.h>
#include <math.h>

#define N_NODES 50000
#define N_EDGES 800000
#define DCH 128
#define N_LAYERS 9
#define N_GRAPHS 256
#define EPSF 1e-5f
#define NCHUNK 196   // ceil(50000/256)
#define SL_SZ 6250   // N_NODES / 8 slices

typedef __attribute__((ext_vector_type(8))) short short8;   // 8 bf16 = 4 VGPRs
typedef __attribute__((ext_vector_type(4))) float floatx4;

static __device__ __forceinline__ unsigned short f2bf(float f) {
    unsigned int u = __float_as_uint(f);
    unsigned int r = (u + 0x7fffu + ((u >> 16) & 1u)) >> 16;  // RNE
    return (unsigned short)r;
}
static __device__ __forceinline__ unsigned int pack_bf2(float a, float b) {
    return (unsigned int)f2bf(a) | ((unsigned int)f2bf(b) << 16);
}
static __device__ __forceinline__ float bflo(unsigned int u) { return __uint_as_float(u << 16); }
static __device__ __forceinline__ float bfhi(unsigned int u) { return __uint_as_float(u & 0xffff0000u); }

// ---------------- CSR build ----------------
__global__ void hist_kernel(const int* __restrict__ dst, int* __restrict__ deg) {
    int t = blockIdx.x * 256 + threadIdx.x;   // grid covers exactly N_EDGES
    atomicAdd(&deg[dst[t]], 1);
}

__global__ __launch_bounds__(256) void chunksum_kernel(const int* __restrict__ deg,
                                                       int* __restrict__ csum) {
    int t = threadIdx.x;
    int i = blockIdx.x * 256 + t;
    int v = (i < N_NODES) ? deg[i] : 0;
    __shared__ int sh[4];
    for (int off = 32; off >= 1; off >>= 1) v += __shfl_down(v, off);
    if ((t & 63) == 0) sh[t >> 6] = v;
    __syncthreads();
    if (t == 0) csum[blockIdx.x] = sh[0] + sh[1] + sh[2] + sh[3];
}

__global__ __launch_bounds__(256) void chunkscan_kernel(const int* __restrict__ csum,
                                                        int* __restrict__ coff) {
    __shared__ int sh[256];
    int t = threadIdx.x;
    sh[t] = (t < NCHUNK) ? csum[t] : 0;
    __syncthreads();
    for (int off = 1; off < 256; off <<= 1) {
        int v = (t >= off) ? sh[t - off] : 0;
        __syncthreads();
        sh[t] += v;
        __syncthreads();
    }
    if (t < NCHUNK) coff[t] = t ? sh[t - 1] : 0;  // exclusive
}

__global__ __launch_bounds__(256) void applyscan_kernel(const int* __restrict__ deg,
                                                        const int* __restrict__ coff,
                                                        int* __restrict__ rowp,
                                                        int* __restrict__ cursor) {
    __shared__ int sh[256];
    int t = threadIdx.x;
    int i = blockIdx.x * 256 + t;
    int d = (i < N_NODES) ? deg[i] : 0;
    sh[t] = d;
    __syncthreads();
    for (int off = 1; off < 256; off <<= 1) {
        int v = (t >= off) ? sh[t - off] : 0;
        __syncthreads();
        sh[t] += v;
        __syncthreads();
    }
    int excl = coff[blockIdx.x] + (t ? sh[t - 1] : 0);
    if (i < N_NODES) {
        rowp[i] = excl;
        cursor[i] = excl;
    }
    if (i == N_NODES - 1) rowp[N_NODES] = N_EDGES;
}

// XCD-sliced scatter: block (chunk, s=blockIdx&7) processes a 1024-edge chunk,
// keeps only edges whose dst is in slice s -> erec writes for slice s stay in
// one ~1.6MB region resident in XCD s's L2 (write-merge before eviction).
__global__ __launch_bounds__(256) void scatter_kernel(const int* __restrict__ src,
                                                      const int* __restrict__ dst,
                                                      const float* __restrict__ eattr,
                                                      int* __restrict__ cursor,
                                                      uint4* __restrict__ erec) {
    int s = blockIdx.x & 7;
    int chunk = blockIdx.x >> 3;
    int e0 = chunk * 1024 + threadIdx.x * 4;
    if (e0 >= N_EDGES) return;
    int4 d4 = *(const int4*)(dst + e0);
#pragma unroll
    for (int k = 0; k < 4; k++) {
        int e = e0 + k;
        int d = (k == 0) ? d4.x : (k == 1) ? d4.y : (k == 2) ? d4.z : d4.w;
        if (d / SL_SZ == s) {
            int p = atomicAdd(&cursor[d], 1);
            float4 a = ((const float4*)eattr)[e];
            erec[p] = make_uint4((unsigned int)src[e], pack_bf2(a.x, a.y), pack_bf2(a.z, a.w), 0u);
        }
    }
}

// ---------------- conv weights -> MFMA B-fragment layout, bf16 ----------------
__global__ __launch_bounds__(256) void wconv_kernel(const float* __restrict__ convW,
                                                    uint4* __restrict__ wb) {
    int tid = blockIdx.x * 256 + threadIdx.x;  // 72 blocks * 256 = 18432 exactly
    int lane = tid & 63;
    int t = (tid >> 6) & 31;
    int layer = tid >> 11;
    int jt = t >> 2, kt = t & 3;
    int quad = lane >> 4, col = lane & 15;
    const float* Wl = convW + (size_t)layer * DCH * DCH;
    int kbase = kt * 32 + quad * 8;
    int ch = jt * 16 + col;
    unsigned int d0 = pack_bf2(Wl[(kbase + 0) * DCH + ch], Wl[(kbase + 1) * DCH + ch]);
    unsigned int d1 = pack_bf2(Wl[(kbase + 2) * DCH + ch], Wl[(kbase + 3) * DCH + ch]);
    unsigned int d2 = pack_bf2(Wl[(kbase + 4) * DCH + ch], Wl[(kbase + 5) * DCH + ch]);
    unsigned int d3 = pack_bf2(Wl[(kbase + 6) * DCH + ch], Wl[(kbase + 7) * DCH + ch]);
    wb[tid] = make_uint4(d0, d1, d2, d3);
}

// ---------------- h0 = x @ Wv (writes fp32 h + bf16 shadow) ----------------
__global__ void h0_kernel(const float* __restrict__ x, const float* __restrict__ Wv,
                          float* __restrict__ h, unsigned int* __restrict__ hbf) {
    int t = blockIdx.x * 256 + threadIdx.x;
    int n = t >> 6, l = t & 63;
    const float* xr = x + n * 13;
    float s0 = 0.f, s1 = 0.f;
#pragma unroll
    for (int j = 0; j < 13; j++) {
        float xv = xr[j];
        s0 = fmaf(xv, Wv[j * 128 + 2 * l], s0);
        s1 = fmaf(xv, Wv[j * 128 + 2 * l + 1], s1);
    }
    ((float2*)h)[n * 64 + l] = make_float2(s0, s1);
    hbf[n * 64 + l] = pack_bf2(s0, s1);
}

// ---------------- per-layer aggregation ----------------
// vbf = bf16( (1+eps)*h + sum_{edges into n} relu(hbf[src] + eattr[e] @ We) )
__global__ __launch_bounds__(256) void aggr_kernel(const float* __restrict__ h,
                                                   const unsigned int* __restrict__ hbf,
                                                   const uint4* __restrict__ erec,
                                                   const int* __restrict__ rowp,
                                                   const float* __restrict__ We,
                                                   unsigned int* __restrict__ vbf) {
    int n = blockIdx.x * 4 + (threadIdx.x >> 6);
    int l = threadIdx.x & 63;
    float w00 = We[0 * 128 + 2 * l], w01 = We[0 * 128 + 2 * l + 1];
    float w10 = We[1 * 128 + 2 * l], w11 = We[1 * 128 + 2 * l + 1];
    float w20 = We[2 * 128 + 2 * l], w21 = We[2 * 128 + 2 * l + 1];
    float w30 = We[3 * 128 + 2 * l], w31 = We[3 * 128 + 2 * l + 1];
    int start = rowp[n], end = rowp[n + 1];
    float a0 = 0.f, a1 = 0.f;
    int e = start;
    for (; e + 4 <= end; e += 4) {
        uint4 r0 = erec[e], r1 = erec[e + 1], r2 = erec[e + 2], r3 = erec[e + 3];
        unsigned int u0 = hbf[(size_t)r0.x * 64 + l];
        unsigned int u1 = hbf[(size_t)r1.x * 64 + l];
        unsigned int u2 = hbf[(size_t)r2.x * 64 + l];
        unsigned int u3 = hbf[(size_t)r3.x * 64 + l];
        float p0 = fmaf(bflo(r0.y), w00, fmaf(bfhi(r0.y), w10, fmaf(bflo(r0.z), w20, bfhi(r0.z) * w30)));
        float p1 = fmaf(bflo(r0.y), w01, fmaf(bfhi(r0.y), w11, fmaf(bflo(r0.z), w21, bfhi(r0.z) * w31)));
        float q0 = fmaf(bflo(r1.y), w00, fmaf(bfhi(r1.y), w10, fmaf(bflo(r1.z), w20, bfhi(r1.z) * w30)));
        float q1 = fmaf(bflo(r1.y), w01, fmaf(bfhi(r1.y), w11, fmaf(bflo(r1.z), w21, bfhi(r1.z) * w31)));
        float s0 = fmaf(bflo(r2.y), w00, fmaf(bfhi(r2.y), w10, fmaf(bflo(r2.z), w20, bfhi(r2.z) * w30)));
        float s1 = fmaf(bflo(r2.y), w01, fmaf(bfhi(r2.y), w11, fmaf(bflo(r2.z), w21, bfhi(r2.z) * w31)));
        float t0 = fmaf(bflo(r3.y), w00, fmaf(bfhi(r3.y), w10, fmaf(bflo(r3.z), w20, bfhi(r3.z) * w30)));
        float t1 = fmaf(bflo(r3.y), w01, fmaf(bfhi(r3.y), w11, fmaf(bflo(r3.z), w21, bfhi(r3.z) * w31)));
        a0 += fmaxf(bflo(u0) + p0, 0.f);
        a1 += fmaxf(bfhi(u0) + p1, 0.f);
        a0 += fmaxf(bflo(u1) + q0, 0.f);
        a1 += fmaxf(bfhi(u1) + q1, 0.f);
        a0 += fmaxf(bflo(u2) + s0, 0.f);
        a1 += fmaxf(bfhi(u2) + s1, 0.f);
        a0 += fmaxf(bflo(u3) + t0, 0.f);
        a1 += fmaxf(bfhi(u3) + t1, 0.f);
    }
    for (; e < end; e++) {
        uint4 r0 = erec[e];
        unsigned int u0 = hbf[(size_t)r0.x * 64 + l];
        float p0 = fmaf(bflo(r0.y), w00, fmaf(bfhi(r0.y), w10, fmaf(bflo(r0.z), w20, bfhi(r0.z) * w30)));
        float p1 = fmaf(bflo(r0.y), w01, fmaf(bfhi(r0.y), w11, fmaf(bflo(r0.z), w21, bfhi(r0.z) * w31)));
        a0 += fmaxf(bflo(u0) + p0, 0.f);
        a1 += fmaxf(bfhi(u0) + p1, 0.f);
    }
    const float2* h2 = (const float2*)h;
    float2 hn = h2[(size_t)n * 64 + l];
    float vx = fmaf(hn.x, 1.f + EPSF, a0);
    float vy = fmaf(hn.y, 1.f + EPSF, a1);
    vbf[(size_t)n * 64 + l] = pack_bf2(vx, vy);
}

// ---------------- per-layer GEMM via MFMA, LDS-transposed epilogue ----------------
#define OLP 132  // padded row: 128 + 4
__global__ __launch_bounds__(256) void gemm_kernel(const unsigned short* __restrict__ vbf,
                                                   const short8* __restrict__ wbL,
                                                   const float* __restrict__ b,
                                                   const float* __restrict__ hin,
                                                   float* __restrict__ hout,
                                                   unsigned short* __restrict__ hbf) {
    __shared__ float ol[64 * OLP];  // 33 KiB
    int tid = threadIdx.x;
    int lane = tid & 63;
    int wave = tid >> 6;
    int nb = blockIdx.x * 64;
    int n0 = nb + wave * 16;
    int col = lane & 15, quad = lane >> 4;
    int arow = n0 + col;
    int arow_c = (arow < N_NODES) ? arow : (N_NODES - 1);
    const short8* va8 = (const short8*)(vbf + (size_t)arow_c * DCH);
    short8 a[4];
#pragma unroll
    for (int kt = 0; kt < 4; kt++) a[kt] = va8[kt * 4 + quad];
#pragma unroll
    for (int jt = 0; jt < 8; jt++) {
        floatx4 acc = {0.f, 0.f, 0.f, 0.f};
#pragma unroll
        for (int kt = 0; kt < 4; kt++) {
            short8 bf = wbL[(jt * 4 + kt) * 64 + lane];
            acc = __builtin_amdgcn_mfma_f32_16x16x32_bf16(a[kt], bf, acc, 0, 0, 0);
        }
        float bv = b[jt * 16 + col];
#pragma unroll
        for (int r = 0; r < 4; r++) {
            ol[(wave * 16 + quad * 4 + r) * OLP + jt * 16 + col] = fmaxf(acc[r] + bv, 0.f);
        }
    }
    __syncthreads();
    const float4* h4 = (const float4*)hin;
    float4* o4 = (float4*)hout;
    uint2* b2 = (uint2*)hbf;
#pragma unroll
    for (int i = 0; i < 8; i++) {
        int idx = i * 256 + tid;            // 0..2047
        int nl = idx >> 5, c4 = idx & 31;   // node-local, float4-chunk
        int node = nb + nl;
        if (node < N_NODES) {
            const float* row = ol + nl * OLP + c4 * 4;
            float4 hh = h4[(size_t)node * 32 + c4];
            float4 r;
            r.x = row[0] + hh.x;
            r.y = row[1] + hh.y;
            r.z = row[2] + hh.z;
            r.w = row[3] + hh.w;
            o4[(size_t)node * 32 + c4] = r;
            b2[(size_t)node * 32 + c4] = make_uint2(pack_bf2(r.x, r.y), pack_bf2(r.z, r.w));
        }
    }
}

// ---------------- graph boundaries (batch is sorted) ----------------
__global__ void bounds_kernel(const int* __restrict__ batch, int* __restrict__ gs) {
    int n = blockIdx.x * 256 + threadIdx.x;
    if (n >= N_NODES) return;
    int bcur = batch[n];
    int prev = (n == 0) ? -1 : batch[n - 1];
    for (int g = prev + 1; g <= bcur; g++) gs[g] = n;
    if (n == N_NODES - 1) {
        for (int g = bcur + 1; g <= N_GRAPHS; g++) gs[g] = N_NODES;
    }
}

// ---------------- sum pool: node-parallel, 8 nodes/thread, segmented atomics ----------------
__global__ __launch_bounds__(256) void pool_kernel(const float* __restrict__ h,
                                                   const int* __restrict__ batch,
                                                   float* __restrict__ sums) {
    int wave = threadIdx.x >> 6, l = threadIdx.x & 63;
    int nbase = (blockIdx.x * 4 + wave) * 8;
    const float2* h2 = (const float2*)h;
    float a0 = 0.f, a1 = 0.f;
    int g = -1;
#pragma unroll
    for (int i = 0; i < 8; i++) {
        int n = nbase + i;
        if (n >= N_NODES) break;
        int bg = batch[n];
        if (bg != g) {
            if (g >= 0) {
                atomicAdd(&sums[g * 128 + 2 * l], a0);
                atomicAdd(&sums[g * 128 + 2 * l + 1], a1);
            }
            g = bg; a0 = 0.f; a1 = 0.f;
        }
        float2 hv = h2[(size_t)n * 64 + l];
        a0 += hv.x; a1 += hv.y;
    }
    if (g >= 0) {
        atomicAdd(&sums[g * 128 + 2 * l], a0);
        atomicAdd(&sums[g * 128 + 2 * l + 1], a1);
    }
}

// ---------------- MLP head (divides pooled sums by count inline) ----------------
__global__ __launch_bounds__(512) void mlp_kernel(const float* __restrict__ sums,
                                                  const int* __restrict__ gs,
                                                  const float* __restrict__ Wh1,
                                                  const float* __restrict__ bh1,
                                                  const float* __restrict__ Wh2,
                                                  const float* __restrict__ bh2,
                                                  float* __restrict__ out) {
    int g = blockIdx.x;
    __shared__ float pl[128];
    __shared__ float red[8];
    int tid = threadIdx.x;
    if (tid < 128) {
        float cnt = fmaxf((float)(gs[g + 1] - gs[g]), 1.0f);
        pl[tid] = sums[g * 128 + tid] / cnt;
    }
    __syncthreads();
    float s = bh1[tid];
#pragma unroll 16
    for (int k = 0; k < 128; k++) s = fmaf(pl[k], Wh1[k * 512 + tid], s);
    float gl = 0.5f * s * (1.0f + erff(s * 0.70710678118654752f));
    float p = gl * Wh2[tid];
    for (int off = 32; off >= 1; off >>= 1) p += __shfl_down(p, off);
    if ((tid & 63) == 0) red[tid >> 6] = p;
    __syncthreads();
    if (tid == 0) {
        float tot = 0.f;
        for (int i = 0; i < 8; i++) tot += red[i];
        out[g] = tot + bh2[0];
    }
}

extern "C" void kernel_launch(void* const* d_in, const int* in_sizes, int n_in,
                              void* d_out, int out_size, void* d_ws, size_t ws_size,
                              hipStream_t stream) {
    const float* x = (const float*)d_in[0];
    const int* ei = (const int*)d_in[1];
    const float* eattr = (const float*)d_in[2];
    const int* batch = (const int*)d_in[3];
    const float* Wv = (const float*)d_in[4];
    const float* We = (const float*)d_in[5];
    const float* convW = (const float*)d_in[6];
    const float* convB = (const float*)d_in[7];
    const float* Wh1 = (const float*)d_in[8];
    const float* bh1 = (const float*)d_in[9];
    const float* Wh2 = (const float*)d_in[10];
    const float* bh2 = (const float*)d_in[11];
    float* out = (float*)d_out;

    const int* src = ei;
    const int* dst = ei + N_EDGES;

    // workspace carve-up (256B aligned) — total ~90 MB
    char* w = (char*)d_ws;
    size_t off = 0;
    auto alloc = [&](size_t bytes) -> char* {
        char* p = w + off;
        off += (bytes + 255) & ~(size_t)255;
        return p;
    };
    float* bufA = (float*)alloc((size_t)N_NODES * DCH * 4);              // h (ping)
    float* bufB = (float*)alloc((size_t)N_NODES * DCH * 4);              // h (pong)
    unsigned int* hbf = (unsigned int*)alloc((size_t)N_NODES * 64 * 4);  // bf16 h shadow
    unsigned int* vbf = (unsigned int*)alloc((size_t)N_NODES * 64 * 4);  // bf16 v
    uint4* wb = (uint4*)alloc((size_t)N_LAYERS * 32 * 64 * 16);          // MFMA W frags
    int* deg = (int*)alloc((size_t)(N_NODES + 1) * 4);
    int* rowp = (int*)alloc((size_t)(N_NODES + 1) * 4);
    int* cursor = (int*)alloc((size_t)(N_NODES + 1) * 4);
    int* csum = (int*)alloc((size_t)NCHUNK * 4);
    int* coff = (int*)alloc((size_t)NCHUNK * 4);
    uint4* erec = (uint4*)alloc((size_t)N_EDGES * 16);
    int* gs = (int*)alloc((size_t)(N_GRAPHS + 1) * 4);
    float* sums = (float*)alloc((size_t)N_GRAPHS * DCH * 4);
    (void)ws_size; (void)n_in; (void)in_sizes; (void)out_size;

    hipMemsetAsync(deg, 0, (size_t)(N_NODES + 1) * 4, stream);
    hipMemsetAsync(sums, 0, (size_t)N_GRAPHS * DCH * 4, stream);

    hist_kernel<<<N_EDGES / 256, 256, 0, stream>>>(dst, deg);
    chunksum_kernel<<<NCHUNK, 256, 0, stream>>>(deg, csum);
    chunkscan_kernel<<<1, 256, 0, stream>>>(csum, coff);
    applyscan_kernel<<<NCHUNK, 256, 0, stream>>>(deg, coff, rowp, cursor);
    scatter_kernel<<<782 * 8, 256, 0, stream>>>(src, dst, eattr, cursor, erec);
    wconv_kernel<<<72, 256, 0, stream>>>(convW, wb);
    h0_kernel<<<N_NODES * 64 / 256, 256, 0, stream>>>(x, Wv, bufA, hbf);
    bounds_kernel<<<(N_NODES + 255) / 256, 256, 0, stream>>>(batch, gs);

    float* hcur = bufA;
    float* hnext = bufB;
    for (int layer = 0; layer < N_LAYERS; layer++) {
        aggr_kernel<<<N_NODES / 4, 256, 0, stream>>>(hcur, hbf, erec, rowp, We, vbf);
        gemm_kernel<<<(N_NODES + 63) / 64, 256, 0, stream>>>(
            (const unsigned short*)vbf, (const short8*)(wb + (size_t)layer * 2048),
            convB + (size_t)layer * DCH, hcur, hnext, (unsigned short*)hbf);
        float* t = hcur; hcur = hnext; hnext = t;
    }

    pool_kernel<<<(N_NODES + 31) / 32, 256, 0, stream>>>(hcur, batch, sums);
    mlp_kernel<<<N_GRAPHS, 512, 0, stream>>>(sums, gs, Wh1, bh1, Wh2, bh2, out);
}